// Round 11
// baseline (204.997 us; speedup 1.0000x reference)
//
#include <hip/hip_runtime.h>
#include <math.h>

constexpr int T  = 2048;
constexpr int Dm = 1024;
constexpr int NH = 16;
constexpr int DH = 64;

typedef unsigned short u16;
typedef short bf16x8 __attribute__((ext_vector_type(8)));
typedef float f32x4 __attribute__((ext_vector_type(4)));

#define MFMA16(a, b, c) __builtin_amdgcn_mfma_f32_16x16x32_bf16((a), (b), (c), 0, 0, 0)

__device__ __forceinline__ float b2f(u16 h) {
    union { unsigned int u; float f; } v; v.u = ((unsigned int)h) << 16; return v.f;
}
__device__ __forceinline__ u16 f2b(float f) {   // RNE fp32->bf16
    union { float f; unsigned int u; } v; v.f = f;
    unsigned int r = v.u + 0x7fffu + ((v.u >> 16) & 1u);
    return (u16)(r >> 16);
}

// ---------------------------------------------------------------------------
__global__ __launch_bounds__(256) void invfreq_kernel(float* __restrict__ invfreq) {
    int c = blockIdx.x * 256 + threadIdx.x;
    if (c < T) {
        float e = (float)(c & ~1) / (float)Dm;
        invfreq[c] = powf(10000.0f, -e);
    }
}

// ---------------------------------------------------------------------------
__global__ __launch_bounds__(256) void ap_kernel(const float* __restrict__ invfreq,
                                                 u16* __restrict__ ap) {
    int p = blockIdx.x * 256 + threadIdx.x;
    int t = blockIdx.y;
    int s = p * 2;
    float sn, cs;
    __sincosf((float)t * invfreq[s], &sn, &cs);
    unsigned int packed = (unsigned int)f2b(sn) | ((unsigned int)f2b(cs) << 16);
    *(unsigned int*)(ap + (size_t)t * T + s) = packed;
}

// ---------------------------------------------------------------------------
__global__ __launch_bounds__(256) void xsplit_kernel(const float* __restrict__ x,
                                                     u16* __restrict__ xhi,
                                                     u16* __restrict__ xlo) {
    size_t i = ((size_t)blockIdx.x * 256 + threadIdx.x) * 4;
    float4 v = *(const float4*)(x + i);
    ushort4 hv, lv;
    hv.x = f2b(v.x); hv.y = f2b(v.y); hv.z = f2b(v.z); hv.w = f2b(v.w);
    lv.x = f2b(v.x - b2f(hv.x)); lv.y = f2b(v.y - b2f(hv.y));
    lv.z = f2b(v.z - b2f(hv.z)); lv.w = f2b(v.w - b2f(hv.w));
    *(ushort4*)(xhi + i) = hv;
    *(ushort4*)(xlo + i) = lv;
}

// ---------------------------------------------------------------------------
__global__ __launch_bounds__(256) void wtrans_kernel(
    const float* __restrict__ Wq, const float* __restrict__ Wk,
    const float* __restrict__ Wv, u16* __restrict__ Wt)
{
    const int z = blockIdx.z;
    const float* W = (z == 0) ? Wq : (z == 1) ? Wk : Wv;
    const int h = blockIdx.y, kc = blockIdx.x * 64;
    const int tid = threadIdx.x;

    __shared__ float Ls[64][65];
    #pragma unroll
    for (int it = 0; it < 4; ++it) {
        int idx = it * 256 + tid;
        int kl = idx >> 4, n4 = (idx & 15) * 4;
        float4 v = *(const float4*)(W + ((size_t)h * Dm + kc + kl) * DH + n4);
        Ls[n4+0][kl] = v.x; Ls[n4+1][kl] = v.y; Ls[n4+2][kl] = v.z; Ls[n4+3][kl] = v.w;
    }
    __syncthreads();

    const int n = tid >> 2, k16 = (tid & 3) * 16;
    union { u16 u[16]; int4 v[2]; } tmp;
    #pragma unroll
    for (int j = 0; j < 16; ++j) tmp.u[j] = f2b(Ls[n][k16 + j]);
    u16* dst = Wt + (((size_t)z * NH + h) * DH + n) * Dm + kc + k16;
    *(int4*)(dst)     = tmp.v[0];
    *(int4*)(dst + 8) = tmp.v[1];
}

// ---------------------------------------------------------------------------
__global__ __launch_bounds__(256) void wout_conv_kernel(const float* __restrict__ W,
                                                        u16* __restrict__ Wb) {
    size_t i = ((size_t)blockIdx.x * 256 + threadIdx.x) * 4;
    float4 v = *(const float4*)(W + i);
    ushort4 hv;
    hv.x = f2b(v.x); hv.y = f2b(v.y); hv.z = f2b(v.z); hv.w = f2b(v.w);
    *(ushort4*)(Wb + i) = hv;
}

// ---------------------------------------------------------------------------
// Fused QKV projection via MFMA + swizzled LDS staging (validated r10).
// ---------------------------------------------------------------------------
__global__ __launch_bounds__(256) void proj_mfma(
    const u16* __restrict__ xhi, const u16* __restrict__ xlo,
    const u16* __restrict__ Wt,
    u16* __restrict__ Qhi, u16* __restrict__ Qlo,
    u16* __restrict__ Khi, u16* __restrict__ Klo,
    u16* __restrict__ Vt)
{
    __shared__ u16 XsH[4096];
    __shared__ u16 XsL[4096];
    __shared__ u16 WsQ[4096];
    __shared__ u16 WsK[4096];
    __shared__ u16 WsV[4096];

    const int t0 = blockIdx.x * 64, h = blockIdx.y;
    const int tid = threadIdx.x, w = tid >> 6, lane = tid & 63;
    const int b = lane & 15, a = lane >> 4;

    const int srow = tid >> 2, sc16 = (tid & 3) * 16;
    const int swz = (srow & 7) << 4;
    const int sb0 = (srow * 128 + sc16 * 2) ^ swz;
    const int sb1 = (srow * 128 + sc16 * 2 + 16) ^ swz;

    const u16* WQb = Wt + ((size_t)0 * NH + h) * DH * Dm;
    const u16* WKb = Wt + ((size_t)1 * NH + h) * DH * Dm;
    const u16* WVb = Wt + ((size_t)2 * NH + h) * DH * Dm;

    f32x4 aq[4], ak[4], av[4];
    #pragma unroll
    for (int ct = 0; ct < 4; ++ct) {
        aq[ct] = (f32x4){0.f, 0.f, 0.f, 0.f};
        ak[ct] = (f32x4){0.f, 0.f, 0.f, 0.f};
        av[ct] = (f32x4){0.f, 0.f, 0.f, 0.f};
    }

    for (int kc = 0; kc < Dm; kc += 64) {
        __syncthreads();
        {
            const u16* gxh = xhi + (size_t)(t0 + srow) * Dm + kc + sc16;
            const u16* gxl = xlo + (size_t)(t0 + srow) * Dm + kc + sc16;
            const u16* gwq = WQb + (size_t)srow * Dm + kc + sc16;
            const u16* gwk = WKb + (size_t)srow * Dm + kc + sc16;
            const u16* gwv = WVb + (size_t)srow * Dm + kc + sc16;
            *(int4*)((char*)XsH + sb0) = *(const int4*)gxh;
            *(int4*)((char*)XsH + sb1) = *(const int4*)(gxh + 8);
            *(int4*)((char*)XsL + sb0) = *(const int4*)gxl;
            *(int4*)((char*)XsL + sb1) = *(const int4*)(gxl + 8);
            *(int4*)((char*)WsQ + sb0) = *(const int4*)gwq;
            *(int4*)((char*)WsQ + sb1) = *(const int4*)(gwq + 8);
            *(int4*)((char*)WsK + sb0) = *(const int4*)gwk;
            *(int4*)((char*)WsK + sb1) = *(const int4*)(gwk + 8);
            *(int4*)((char*)WsV + sb0) = *(const int4*)gwv;
            *(int4*)((char*)WsV + sb1) = *(const int4*)(gwv + 8);
        }
        __syncthreads();

        bf16x8 ah[2], al[2];
        #pragma unroll
        for (int ks = 0; ks < 2; ++ks) {
            int row = 16 * w + b;
            int byt = (row * 128 + ks * 64 + a * 16) ^ ((row & 7) << 4);
            ah[ks] = *(const bf16x8*)((const char*)XsH + byt);
            al[ks] = *(const bf16x8*)((const char*)XsL + byt);
        }
        #pragma unroll
        for (int ct = 0; ct < 4; ++ct) {
            #pragma unroll
            for (int ks = 0; ks < 2; ++ks) {
                int row = 16 * ct + b;
                int byt = (row * 128 + ks * 64 + a * 16) ^ ((row & 7) << 4);
                bf16x8 bq = *(const bf16x8*)((const char*)WsQ + byt);
                bf16x8 bk = *(const bf16x8*)((const char*)WsK + byt);
                bf16x8 bv = *(const bf16x8*)((const char*)WsV + byt);
                aq[ct] = MFMA16(ah[ks], bq, aq[ct]);
                aq[ct] = MFMA16(al[ks], bq, aq[ct]);
                ak[ct] = MFMA16(ah[ks], bk, ak[ct]);
                ak[ct] = MFMA16(al[ks], bk, ak[ct]);
                av[ct] = MFMA16(ah[ks], bv, av[ct]);
            }
        }
    }

    const size_t base = (size_t)h * T * DH;
    #pragma unroll
    for (int ct = 0; ct < 4; ++ct) {
        #pragma unroll
        for (int r = 0; r < 4; ++r) {
            int t = t0 + 16 * w + a * 4 + r;
            size_t off = base + (size_t)t * DH + 16 * ct + b;
            float fq = aq[ct][r];
            u16 qv = f2b(fq);
            Qhi[off] = qv; Qlo[off] = f2b(fq - b2f(qv));
            float fk = ak[ct][r];
            u16 kv = f2b(fk);
            Khi[off] = kv; Klo[off] = f2b(fk - b2f(kv));
            Vt[((size_t)h * DH + 16 * ct + b) * T + t] = f2b(av[ct][r]);
        }
    }
}

// ---------------------------------------------------------------------------
// MFMA flash attention with optional split-K. KS=1: write normalized bf16 Yc.
// KS=2: write unnormalized bf16 partial O + (m,l) per row; combine merges.
// Defer-max (THR=8) skips O-rescale when tile max is within old running max.
// ---------------------------------------------------------------------------
template<int KS>
__global__ __launch_bounds__(256) void flash_mfma(
    const u16* __restrict__ Qhi, const u16* __restrict__ Qlo,
    const u16* __restrict__ Khi, const u16* __restrict__ Klo,
    const u16* __restrict__ Vt,  const u16* __restrict__ AP,
    u16* __restrict__ outp, float2* __restrict__ ml)
{
    __shared__ u16 KsH[4096];
    __shared__ u16 KsL[4096];
    __shared__ u16 Vs[4096];
    __shared__ u16 Ps[4][1024];

    const int h = blockIdx.y, t0 = blockIdx.x * 64;
    const int split = (KS == 2) ? blockIdx.z : 0;
    const int s_begin = split * (T / KS), s_end = s_begin + T / KS;
    const int tid = threadIdx.x, w = tid >> 6, lane = tid & 63;
    const int b = lane & 15, a = lane >> 4;

    const size_t hTD = (size_t)h * T * DH;

    const size_t qoff = hTD + (size_t)(t0 + 16*w + b) * DH + a * 8;
    bf16x8 qh[2], ql[2];
    qh[0] = *(const bf16x8*)(Qhi + qoff);
    qh[1] = *(const bf16x8*)(Qhi + qoff + 32);
    ql[0] = *(const bf16x8*)(Qlo + qoff);
    ql[1] = *(const bf16x8*)(Qlo + qoff + 32);

    f32x4 oacc[4];
    float m_run[4], l_run[4];
    #pragma unroll
    for (int i = 0; i < 4; ++i) {
        oacc[i] = (f32x4){0.f, 0.f, 0.f, 0.f};
        m_run[i] = -INFINITY; l_run[i] = 0.f;
    }

    const int srow = tid >> 2, sc16 = (tid & 3) * 16;
    const int swz = (srow & 7) << 4;
    const int sb0 = (srow * 128 + sc16 * 2) ^ swz;
    const int sb1 = (srow * 128 + sc16 * 2 + 16) ^ swz;

    for (int s0 = s_begin; s0 < s_end; s0 += 64) {
        __syncthreads();
        {
            const u16* gkh = Khi + hTD + (size_t)(s0 + srow) * DH + sc16;
            const u16* gkl = Klo + hTD + (size_t)(s0 + srow) * DH + sc16;
            const u16* gv  = Vt  + hTD + (size_t)srow * T + s0 + sc16;
            *(int4*)((char*)KsH + sb0) = *(const int4*)gkh;
            *(int4*)((char*)KsH + sb1) = *(const int4*)(gkh + 8);
            *(int4*)((char*)KsL + sb0) = *(const int4*)gkl;
            *(int4*)((char*)KsL + sb1) = *(const int4*)(gkl + 8);
            *(int4*)((char*)Vs  + sb0) = *(const int4*)gv;
            *(int4*)((char*)Vs  + sb1) = *(const int4*)(gv + 8);
        }
        __syncthreads();

        f32x4 acc[4];
        #pragma unroll
        for (int ct = 0; ct < 4; ++ct) acc[ct] = (f32x4){0.f, 0.f, 0.f, 0.f};
        #pragma unroll
        for (int ct = 0; ct < 4; ++ct) {
            #pragma unroll
            for (int ks = 0; ks < 2; ++ks) {
                int row = 16 * ct + b;
                int byt = (row * 128 + ks * 64 + a * 16) ^ ((row & 7) << 4);
                bf16x8 kh = *(const bf16x8*)((const char*)KsH + byt);
                bf16x8 kl = *(const bf16x8*)((const char*)KsL + byt);
                acc[ct] = MFMA16(qh[ks], kh, acc[ct]);
                acc[ct] = MFMA16(qh[ks], kl, acc[ct]);
                acc[ct] = MFMA16(ql[ks], kh, acc[ct]);
            }
        }

        #pragma unroll
        for (int r = 0; r < 4; ++r) {
            int t = t0 + 16 * w + a * 4 + r;
            const u16* aprow = AP + (size_t)t * T + s0 + b;
            #pragma unroll
            for (int ct = 0; ct < 4; ++ct)
                acc[ct][r] += b2f(aprow[16 * ct]);
        }

        #pragma unroll
        for (int r = 0; r < 4; ++r) {
            float mx = fmaxf(fmaxf(acc[0][r], acc[1][r]), fmaxf(acc[2][r], acc[3][r]));
            #pragma unroll
            for (int msk = 8; msk > 0; msk >>= 1) mx = fmaxf(mx, __shfl_xor(mx, msk));
            float mnew;
            bool skip = (mx <= m_run[r] + 8.f);   // defer-max (HK THR=8)
            if (skip) {
                mnew = m_run[r];
            } else {
                mnew = fmaxf(m_run[r], mx);
                float alpha = __expf(m_run[r] - mnew);   // first tile: 0
                l_run[r] *= alpha;
                oacc[0][r] *= alpha; oacc[1][r] *= alpha;
                oacc[2][r] *= alpha; oacc[3][r] *= alpha;
                m_run[r] = mnew;
            }
            float p0 = __expf(acc[0][r] - mnew);
            float p1 = __expf(acc[1][r] - mnew);
            float p2 = __expf(acc[2][r] - mnew);
            float p3 = __expf(acc[3][r] - mnew);
            float rs = p0 + p1 + p2 + p3;
            #pragma unroll
            for (int msk = 8; msk > 0; msk >>= 1) rs += __shfl_xor(rs, msk);
            l_run[r] += rs;
            int rl = a * 4 + r;
            int rbase = rl * 128, rswz = (rl & 7) << 4;
            *(u16*)((char*)Ps[w] + ((rbase + (b     ) * 2) ^ rswz)) = f2b(p0);
            *(u16*)((char*)Ps[w] + ((rbase + (b + 16) * 2) ^ rswz)) = f2b(p1);
            *(u16*)((char*)Ps[w] + ((rbase + (b + 32) * 2) ^ rswz)) = f2b(p2);
            *(u16*)((char*)Ps[w] + ((rbase + (b + 48) * 2) ^ rswz)) = f2b(p3);
        }

        bf16x8 pa[2];
        #pragma unroll
        for (int ks = 0; ks < 2; ++ks) {
            int byt = (b * 128 + ks * 64 + a * 16) ^ ((b & 7) << 4);
            pa[ks] = *(const bf16x8*)((const char*)Ps[w] + byt);
        }
        #pragma unroll
        for (int dt = 0; dt < 4; ++dt) {
            #pragma unroll
            for (int ks = 0; ks < 2; ++ks) {
                int row = 16 * dt + b;
                int byt = (row * 128 + ks * 64 + a * 16) ^ ((row & 7) << 4);
                bf16x8 vf = *(const bf16x8*)((const char*)Vs + byt);
                oacc[dt] = MFMA16(pa[ks], vf, oacc[dt]);
            }
        }
    }

    if (KS == 1) {
        #pragma unroll
        for (int r = 0; r < 4; ++r) {
            float inv = 1.f / l_run[r];
            int t = t0 + 16 * w + a * 4 + r;
            #pragma unroll
            for (int dt = 0; dt < 4; ++dt)
                outp[(size_t)t * Dm + h * DH + 16 * dt + b] = f2b(oacc[dt][r] * inv);
        }
    } else {
        const size_t pbase = ((size_t)split * NH + h) * T;
        #pragma unroll
        for (int r = 0; r < 4; ++r) {
            int t = t0 + 16 * w + a * 4 + r;
            #pragma unroll
            for (int dt = 0; dt < 4; ++dt)
                outp[(pbase + t) * DH + 16 * dt + b] = f2b(oacc[dt][r]);
            if (b == 0) ml[pbase + t] = make_float2(m_run[r], l_run[r]);
        }
    }
}

// ---------------------------------------------------------------------------
// Combine split-K partials: Yc = (w0*O0 + w1*O1) / (w0*l0 + w1*l1)
// ---------------------------------------------------------------------------
__global__ __launch_bounds__(256) void flash_combine(
    const u16* __restrict__ Opart, const float2* __restrict__ ml,
    u16* __restrict__ Ycb)
{
    int idx = blockIdx.x * 256 + threadIdx.x;          // NH*T*8 total
    int h = idx >> 14;                                 // / (T*8)
    int rem = idx & 16383;
    int t = rem >> 3;
    int d8 = (rem & 7) * 8;

    const size_t r0 = ((size_t)0 * NH + h) * T + t;
    const size_t r1 = ((size_t)1 * NH + h) * T + t;
    float2 ml0 = ml[r0], ml1 = ml[r1];
    float m = fmaxf(ml0.x, ml1.x);
    float w0 = __expf(ml0.x - m), w1 = __expf(ml1.x - m);
    float inv = 1.f / (w0 * ml0.y + w1 * ml1.y);
    w0 *= inv; w1 *= inv;

    union { u16 u[8]; int4 v; } o0, o1, yo;
    o0.v = *(const int4*)(Opart + r0 * DH + d8);
    o1.v = *(const int4*)(Opart + r1 * DH + d8);
    #pragma unroll
    for (int j = 0; j < 8; ++j)
        yo.u[j] = f2b(b2f(o0.u[j]) * w0 + b2f(o1.u[j]) * w1);
    *(int4*)(Ycb + (size_t)t * Dm + h * DH + d8) = yo.v;
}

// ---------------------------------------------------------------------------
// Head-15 scores via MFMA (split QK) + AP -> fp32 S   (validated r9/r10)
// ---------------------------------------------------------------------------
__global__ __launch_bounds__(256) void score_mfma(
    const u16* __restrict__ Qhi, const u16* __restrict__ Qlo,
    const u16* __restrict__ Khi, const u16* __restrict__ Klo,
    const u16* __restrict__ AP, float* __restrict__ S)
{
    __shared__ u16 KsH[4096];
    __shared__ u16 KsL[4096];

    const int h = NH - 1;
    const int s0 = blockIdx.x * 64, t0 = blockIdx.y * 64;
    const int tid = threadIdx.x, w = tid >> 6, lane = tid & 63;
    const int b = lane & 15, a = lane >> 4;
    const size_t hTD = (size_t)h * T * DH;

    {
        const int srow = tid >> 2, sc16 = (tid & 3) * 16;
        const int swz = (srow & 7) << 4;
        const int sb0 = (srow * 128 + sc16 * 2) ^ swz;
        const int sb1 = (srow * 128 + sc16 * 2 + 16) ^ swz;
        const u16* gkh = Khi + hTD + (size_t)(s0 + srow) * DH + sc16;
        const u16* gkl = Klo + hTD + (size_t)(s0 + srow) * DH + sc16;
        *(int4*)((char*)KsH + sb0) = *(const int4*)gkh;
        *(int4*)((char*)KsH + sb1) = *(const int4*)(gkh + 8);
        *(int4*)((char*)KsL + sb0) = *(const int4*)gkl;
        *(int4*)((char*)KsL + sb1) = *(const int4*)(gkl + 8);
    }

    const size_t qoff = hTD + (size_t)(t0 + 16*w + b) * DH + a * 8;
    bf16x8 qh[2], ql[2];
    qh[0] = *(const bf16x8*)(Qhi + qoff);
    qh[1] = *(const bf16x8*)(Qhi + qoff + 32);
    ql[0] = *(const bf16x8*)(Qlo + qoff);
    ql[1] = *(const bf16x8*)(Qlo + qoff + 32);
    __syncthreads();

    f32x4 acc[4];
    #pragma unroll
    for (int ct = 0; ct < 4; ++ct) acc[ct] = (f32x4){0.f, 0.f, 0.f, 0.f};
    #pragma unroll
    for (int ct = 0; ct < 4; ++ct) {
        #pragma unroll
        for (int ks = 0; ks < 2; ++ks) {
            int row = 16 * ct + b;
            int byt = (row * 128 + ks * 64 + a * 16) ^ ((row & 7) << 4);
            bf16x8 kh = *(const bf16x8*)((const char*)KsH + byt);
            bf16x8 kl = *(const bf16x8*)((const char*)KsL + byt);
            acc[ct] = MFMA16(qh[ks], kh, acc[ct]);
            acc[ct] = MFMA16(qh[ks], kl, acc[ct]);
            acc[ct] = MFMA16(ql[ks], kh, acc[ct]);
        }
    }

    #pragma unroll
    for (int r = 0; r < 4; ++r) {
        int t = t0 + 16 * w + a * 4 + r;
        const u16* aprow = AP + (size_t)t * T + s0 + b;
        #pragma unroll
        for (int ct = 0; ct < 4; ++ct)
            S[(size_t)t * T + s0 + 16 * ct + b] = acc[ct][r] + b2f(aprow[16 * ct]);
    }
}

// ---------------------------------------------------------------------------
__global__ __launch_bounds__(256) void softmax_kernel(float* __restrict__ Sbase)
{
    float* S = Sbase + (long)blockIdx.x * T;
    const int tid = threadIdx.x;
    const int wid = tid >> 6, lane = tid & 63;

    float4 v0 = *(const float4*)(S + tid*8);
    float4 v1 = *(const float4*)(S + tid*8 + 4);

    float m = fmaxf(fmaxf(fmaxf(v0.x, v0.y), fmaxf(v0.z, v0.w)),
                    fmaxf(fmaxf(v1.x, v1.y), fmaxf(v1.z, v1.w)));
    #pragma unroll
    for (int o = 32; o > 0; o >>= 1) m = fmaxf(m, __shfl_xor(m, o));

    __shared__ float redm[4];
    __shared__ float reds[4];
    if (lane == 0) redm[wid] = m;
    __syncthreads();
    m = fmaxf(fmaxf(redm[0], redm[1]), fmaxf(redm[2], redm[3]));

    v0.x = expf(v0.x - m); v0.y = expf(v0.y - m); v0.z = expf(v0.z - m); v0.w = expf(v0.w - m);
    v1.x = expf(v1.x - m); v1.y = expf(v1.y - m); v1.z = expf(v1.z - m); v1.w = expf(v1.w - m);

    float s = v0.x + v0.y + v0.z + v0.w + v1.x + v1.y + v1.z + v1.w;
    #pragma unroll
    for (int o = 32; o > 0; o >>= 1) s += __shfl_xor(s, o);
    if (lane == 0) reds[wid] = s;
    __syncthreads();
    s = reds[0] + reds[1] + reds[2] + reds[3];

    float inv = 1.0f / s;
    v0.x *= inv; v0.y *= inv; v0.z *= inv; v0.w *= inv;
    v1.x *= inv; v1.y *= inv; v1.z *= inv; v1.w *= inv;
    *(float4*)(S + tid*8)     = v0;
    *(float4*)(S + tid*8 + 4) = v1;
}

// ---------------------------------------------------------------------------
// y = Ycb(bf16) @ Woutb(bf16)^T via MFMA with LDS staging (validated r10)
// ---------------------------------------------------------------------------
__global__ __launch_bounds__(256) void gemm_out_mfma(
    const u16* __restrict__ Ycb, const u16* __restrict__ Wb,
    float* __restrict__ y)
{
    __shared__ u16 As[4096];
    __shared__ u16 Bs[4096];

    const int n0 = blockIdx.x * 64, t0 = blockIdx.y * 64;
    const int tid = threadIdx.x, w = tid >> 6, lane = tid & 63;
    const int b = lane & 15, a = lane >> 4;

    const int srow = tid >> 2, sc16 = (tid & 3) * 16;
    const int swz = (srow & 7) << 4;
    const int sb0 = (srow * 128 + sc16 * 2) ^ swz;
    const int sb1 = (srow * 128 + sc16 * 2 + 16) ^ swz;

    f32x4 acc[4];
    #pragma unroll
    for (int ct = 0; ct < 4; ++ct) acc[ct] = (f32x4){0.f, 0.f, 0.f, 0.f};

    for (int kc = 0; kc < Dm; kc += 64) {
        __syncthreads();
        {
            const u16* ga = Ycb + (size_t)(t0 + srow) * Dm + kc + sc16;
            const u16* gb = Wb  + (size_t)(n0 + srow) * Dm + kc + sc16;
            *(int4*)((char*)As + sb0) = *(const int4*)ga;
            *(int4*)((char*)As + sb1) = *(const int4*)(ga + 8);
            *(int4*)((char*)Bs + sb0) = *(const int4*)gb;
            *(int4*)((char*)Bs + sb1) = *(const int4*)(gb + 8);
        }
        __syncthreads();

        bf16x8 af[2];
        #pragma unroll
        for (int ks = 0; ks < 2; ++ks) {
            int row = 16 * w + b;
            int byt = (row * 128 + ks * 64 + a * 16) ^ ((row & 7) << 4);
            af[ks] = *(const bf16x8*)((const char*)As + byt);
        }
        #pragma unroll
        for (int ct = 0; ct < 4; ++ct) {
            #pragma unroll
            for (int ks = 0; ks < 2; ++ks) {
                int row = 16 * ct + b;
                int byt = (row * 128 + ks * 64 + a * 16) ^ ((row & 7) << 4);
                bf16x8 bw = *(const bf16x8*)((const char*)Bs + byt);
                acc[ct] = MFMA16(af[ks], bw, acc[ct]);
            }
        }
    }

    #pragma unroll
    for (int r = 0; r < 4; ++r) {
        int t = t0 + 16 * w + a * 4 + r;
        #pragma unroll
        for (int ct = 0; ct < 4; ++ct)
            y[(size_t)t * Dm + n0 + 16 * ct + b] = acc[ct][r];
    }
}

// ---------------------------------------------------------------------------
extern "C" void kernel_launch(void* const* d_in, const int* in_sizes, int n_in,
                              void* d_out, int out_size, void* d_ws, size_t ws_size,
                              hipStream_t stream)
{
    const float* x    = (const float*)d_in[0];
    const float* Wq   = (const float*)d_in[1];
    const float* Wk   = (const float*)d_in[2];
    const float* Wv   = (const float*)d_in[3];
    const float* Wout = (const float*)d_in[4];

    float* out      = (float*)d_out;
    float* y_out    = out;
    float* attn_out = out + (long)T * Dm;

    // ---- workspace layout ----
    char* ws = (char*)d_ws;
    const size_t MB = 1024 * 1024;
    float* invfreq = (float*)ws;                       // 8 KB
    u16* Qhi = (u16*)(ws + 8192);                      // 4 MB each
    u16* Qlo = (u16*)(ws + 8192 + 4 * MB);
    u16* Khi = (u16*)(ws + 8192 + 8 * MB);
    u16* Klo = (u16*)(ws + 8192 + 12 * MB);
    u16* Vt  = (u16*)(ws + 8192 + 16 * MB);            // 4 MB
    char* C  = ws + 8192 + 20 * MB;                    // 14 MB union region
    u16* xhi = (u16*)(C);                              // phase 1
    u16* xlo = (u16*)(C + 4 * MB);
    u16* Wtb = (u16*)(C + 8 * MB);
    u16* APt   = (u16*)(C);                            // phase 2
    u16* Ycb   = (u16*)(C + 8 * MB);
    u16* Woutb = (u16*)(C + 12 * MB);
    // split-K extras (only if ws_size permits):
    u16*    Opart = (u16*)(C + 14 * MB);               // 8 MB (2 x [NH][T][DH])
    float2* mlbuf = (float2*)(C + 22 * MB);            // 512 KB
    const size_t NEED_SPLIT = 8192 + 20 * MB + 23 * MB;
    const bool do_split = ws_size >= NEED_SPLIT;

    invfreq_kernel<<<dim3(8), dim3(256), 0, stream>>>(invfreq);

    xsplit_kernel<<<dim3((T * Dm / 4) / 256), dim3(256), 0, stream>>>(x, xhi, xlo);
    wtrans_kernel<<<dim3(Dm / 64, NH, 3), dim3(256), 0, stream>>>(Wq, Wk, Wv, Wtb);

    proj_mfma<<<dim3(T / 64, NH), dim3(256), 0, stream>>>(
        xhi, xlo, Wtb, Qhi, Qlo, Khi, Klo, Vt);

    ap_kernel<<<dim3(T / 512, T), dim3(256), 0, stream>>>(invfreq, APt);
    wout_conv_kernel<<<dim3((Dm * Dm / 4) / 256), dim3(256), 0, stream>>>(Wout, Woutb);

    if (do_split) {
        flash_mfma<2><<<dim3(T / 64, NH, 2), dim3(256), 0, stream>>>(
            Qhi, Qlo, Khi, Klo, Vt, APt, Opart, mlbuf);
        flash_combine<<<dim3(NH * T * 8 / 256), dim3(256), 0, stream>>>(
            Opart, mlbuf, Ycb);
    } else {
        flash_mfma<1><<<dim3(T / 64, NH, 1), dim3(256), 0, stream>>>(
            Qhi, Qlo, Khi, Klo, Vt, APt, Ycb, nullptr);
    }

    score_mfma<<<dim3(T / 64, T / 64), dim3(256), 0, stream>>>(
        Qhi, Qlo, Khi, Klo, APt, attn_out);
    softmax_kernel<<<dim3(T), dim3(256), 0, stream>>>(attn_out);

    gemm_out_mfma<<<dim3(Dm / 64, T / 64), dim3(256), 0, stream>>>(Ycb, Woutb, y_out);
}

// Round 12
// 198.801 us; speedup vs baseline: 1.0312x; 1.0312x over previous
//
#include <hip/hip_runtime.h>
#include <math.h>

constexpr int T  = 2048;
constexpr int Dm = 1024;
constexpr int NH = 16;
constexpr int DH = 64;

typedef unsigned short u16;
typedef short bf16x8 __attribute__((ext_vector_type(8)));
typedef float f32x4 __attribute__((ext_vector_type(4)));

#define MFMA16(a, b, c) __builtin_amdgcn_mfma_f32_16x16x32_bf16((a), (b), (c), 0, 0, 0)

__device__ __forceinline__ float b2f(u16 h) {
    union { unsigned int u; float f; } v; v.u = ((unsigned int)h) << 16; return v.f;
}
__device__ __forceinline__ u16 f2b(float f) {   // RNE fp32->bf16
    union { float f; unsigned int u; } v; v.f = f;
    unsigned int r = v.u + 0x7fffu + ((v.u >> 16) & 1u);
    return (u16)(r >> 16);
}

// ---------------------------------------------------------------------------
__global__ __launch_bounds__(256) void invfreq_kernel(float* __restrict__ invfreq) {
    int c = blockIdx.x * 256 + threadIdx.x;
    if (c < T) {
        float e = (float)(c & ~1) / (float)Dm;
        invfreq[c] = powf(10000.0f, -e);
    }
}

// ---------------------------------------------------------------------------
__global__ __launch_bounds__(256) void ap_kernel(const float* __restrict__ invfreq,
                                                 u16* __restrict__ ap) {
    int p = blockIdx.x * 256 + threadIdx.x;
    int t = blockIdx.y;
    int s = p * 2;
    float sn, cs;
    __sincosf((float)t * invfreq[s], &sn, &cs);
    unsigned int packed = (unsigned int)f2b(sn) | ((unsigned int)f2b(cs) << 16);
    *(unsigned int*)(ap + (size_t)t * T + s) = packed;
}

// ---------------------------------------------------------------------------
__global__ __launch_bounds__(256) void xsplit_kernel(const float* __restrict__ x,
                                                     u16* __restrict__ xhi,
                                                     u16* __restrict__ xlo) {
    size_t i = ((size_t)blockIdx.x * 256 + threadIdx.x) * 4;
    float4 v = *(const float4*)(x + i);
    ushort4 hv, lv;
    hv.x = f2b(v.x); hv.y = f2b(v.y); hv.z = f2b(v.z); hv.w = f2b(v.w);
    lv.x = f2b(v.x - b2f(hv.x)); lv.y = f2b(v.y - b2f(hv.y));
    lv.z = f2b(v.z - b2f(hv.z)); lv.w = f2b(v.w - b2f(hv.w));
    *(ushort4*)(xhi + i) = hv;
    *(ushort4*)(xlo + i) = lv;
}

// ---------------------------------------------------------------------------
__global__ __launch_bounds__(256) void wtrans_kernel(
    const float* __restrict__ Wq, const float* __restrict__ Wk,
    const float* __restrict__ Wv, u16* __restrict__ Wt)
{
    const int z = blockIdx.z;
    const float* W = (z == 0) ? Wq : (z == 1) ? Wk : Wv;
    const int h = blockIdx.y, kc = blockIdx.x * 64;
    const int tid = threadIdx.x;

    __shared__ float Ls[64][65];
    #pragma unroll
    for (int it = 0; it < 4; ++it) {
        int idx = it * 256 + tid;
        int kl = idx >> 4, n4 = (idx & 15) * 4;
        float4 v = *(const float4*)(W + ((size_t)h * Dm + kc + kl) * DH + n4);
        Ls[n4+0][kl] = v.x; Ls[n4+1][kl] = v.y; Ls[n4+2][kl] = v.z; Ls[n4+3][kl] = v.w;
    }
    __syncthreads();

    const int n = tid >> 2, k16 = (tid & 3) * 16;
    union { u16 u[16]; int4 v[2]; } tmp;
    #pragma unroll
    for (int j = 0; j < 16; ++j) tmp.u[j] = f2b(Ls[n][k16 + j]);
    u16* dst = Wt + (((size_t)z * NH + h) * DH + n) * Dm + kc + k16;
    *(int4*)(dst)     = tmp.v[0];
    *(int4*)(dst + 8) = tmp.v[1];
}

// ---------------------------------------------------------------------------
__global__ __launch_bounds__(256) void wout_conv_kernel(const float* __restrict__ W,
                                                        u16* __restrict__ Wb) {
    size_t i = ((size_t)blockIdx.x * 256 + threadIdx.x) * 4;
    float4 v = *(const float4*)(W + i);
    ushort4 hv;
    hv.x = f2b(v.x); hv.y = f2b(v.y); hv.z = f2b(v.z); hv.w = f2b(v.w);
    *(ushort4*)(Wb + i) = hv;
}

// ---------------------------------------------------------------------------
// Fused QKV projection via MFMA + swizzled LDS staging (validated r10).
// ---------------------------------------------------------------------------
__global__ __launch_bounds__(256) void proj_mfma(
    const u16* __restrict__ xhi, const u16* __restrict__ xlo,
    const u16* __restrict__ Wt,
    u16* __restrict__ Qhi, u16* __restrict__ Qlo,
    u16* __restrict__ Khi, u16* __restrict__ Klo,
    u16* __restrict__ Vt)
{
    __shared__ u16 XsH[4096];
    __shared__ u16 XsL[4096];
    __shared__ u16 WsQ[4096];
    __shared__ u16 WsK[4096];
    __shared__ u16 WsV[4096];

    const int t0 = blockIdx.x * 64, h = blockIdx.y;
    const int tid = threadIdx.x, w = tid >> 6, lane = tid & 63;
    const int b = lane & 15, a = lane >> 4;

    const int srow = tid >> 2, sc16 = (tid & 3) * 16;
    const int swz = (srow & 7) << 4;
    const int sb0 = (srow * 128 + sc16 * 2) ^ swz;
    const int sb1 = (srow * 128 + sc16 * 2 + 16) ^ swz;

    const u16* WQb = Wt + ((size_t)0 * NH + h) * DH * Dm;
    const u16* WKb = Wt + ((size_t)1 * NH + h) * DH * Dm;
    const u16* WVb = Wt + ((size_t)2 * NH + h) * DH * Dm;

    f32x4 aq[4], ak[4], av[4];
    #pragma unroll
    for (int ct = 0; ct < 4; ++ct) {
        aq[ct] = (f32x4){0.f, 0.f, 0.f, 0.f};
        ak[ct] = (f32x4){0.f, 0.f, 0.f, 0.f};
        av[ct] = (f32x4){0.f, 0.f, 0.f, 0.f};
    }

    for (int kc = 0; kc < Dm; kc += 64) {
        __syncthreads();
        {
            const u16* gxh = xhi + (size_t)(t0 + srow) * Dm + kc + sc16;
            const u16* gxl = xlo + (size_t)(t0 + srow) * Dm + kc + sc16;
            const u16* gwq = WQb + (size_t)srow * Dm + kc + sc16;
            const u16* gwk = WKb + (size_t)srow * Dm + kc + sc16;
            const u16* gwv = WVb + (size_t)srow * Dm + kc + sc16;
            *(int4*)((char*)XsH + sb0) = *(const int4*)gxh;
            *(int4*)((char*)XsH + sb1) = *(const int4*)(gxh + 8);
            *(int4*)((char*)XsL + sb0) = *(const int4*)gxl;
            *(int4*)((char*)XsL + sb1) = *(const int4*)(gxl + 8);
            *(int4*)((char*)WsQ + sb0) = *(const int4*)gwq;
            *(int4*)((char*)WsQ + sb1) = *(const int4*)(gwq + 8);
            *(int4*)((char*)WsK + sb0) = *(const int4*)gwk;
            *(int4*)((char*)WsK + sb1) = *(const int4*)(gwk + 8);
            *(int4*)((char*)WsV + sb0) = *(const int4*)gwv;
            *(int4*)((char*)WsV + sb1) = *(const int4*)(gwv + 8);
        }
        __syncthreads();

        bf16x8 ah[2], al[2];
        #pragma unroll
        for (int ks = 0; ks < 2; ++ks) {
            int row = 16 * w + b;
            int byt = (row * 128 + ks * 64 + a * 16) ^ ((row & 7) << 4);
            ah[ks] = *(const bf16x8*)((const char*)XsH + byt);
            al[ks] = *(const bf16x8*)((const char*)XsL + byt);
        }
        #pragma unroll
        for (int ct = 0; ct < 4; ++ct) {
            #pragma unroll
            for (int ks = 0; ks < 2; ++ks) {
                int row = 16 * ct + b;
                int byt = (row * 128 + ks * 64 + a * 16) ^ ((row & 7) << 4);
                bf16x8 bq = *(const bf16x8*)((const char*)WsQ + byt);
                bf16x8 bk = *(const bf16x8*)((const char*)WsK + byt);
                bf16x8 bv = *(const bf16x8*)((const char*)WsV + byt);
                aq[ct] = MFMA16(ah[ks], bq, aq[ct]);
                aq[ct] = MFMA16(al[ks], bq, aq[ct]);
                ak[ct] = MFMA16(ah[ks], bk, ak[ct]);
                ak[ct] = MFMA16(al[ks], bk, ak[ct]);
                av[ct] = MFMA16(ah[ks], bv, av[ct]);
            }
        }
    }

    const size_t base = (size_t)h * T * DH;
    #pragma unroll
    for (int ct = 0; ct < 4; ++ct) {
        #pragma unroll
        for (int r = 0; r < 4; ++r) {
            int t = t0 + 16 * w + a * 4 + r;
            size_t off = base + (size_t)t * DH + 16 * ct + b;
            float fq = aq[ct][r];
            u16 qv = f2b(fq);
            Qhi[off] = qv; Qlo[off] = f2b(fq - b2f(qv));
            float fk = ak[ct][r];
            u16 kv = f2b(fk);
            Khi[off] = kv; Klo[off] = f2b(fk - b2f(kv));
            Vt[((size_t)h * DH + 16 * ct + b) * T + t] = f2b(av[ct][r]);
        }
    }
}

// ---------------------------------------------------------------------------
// MFMA flash attention, split-K over the s-range (2 splits). Each split
// writes unnormalized bf16 partial O + (m,l) per row; combine merges.
// Softmax update = r10-validated form (defer-max reverted: it regressed).
// ---------------------------------------------------------------------------
__global__ __launch_bounds__(256) void flash_mfma_split(
    const u16* __restrict__ Qhi, const u16* __restrict__ Qlo,
    const u16* __restrict__ Khi, const u16* __restrict__ Klo,
    const u16* __restrict__ Vt,  const u16* __restrict__ AP,
    u16* __restrict__ Opart, float2* __restrict__ ml)
{
    __shared__ u16 KsH[4096];
    __shared__ u16 KsL[4096];
    __shared__ u16 Vs[4096];
    __shared__ u16 Ps[4][1024];

    const int h = blockIdx.y, t0 = blockIdx.x * 64;
    const int split = blockIdx.z;
    const int s_begin = split * (T / 2), s_end = s_begin + T / 2;
    const int tid = threadIdx.x, w = tid >> 6, lane = tid & 63;
    const int b = lane & 15, a = lane >> 4;

    const size_t hTD = (size_t)h * T * DH;

    const size_t qoff = hTD + (size_t)(t0 + 16*w + b) * DH + a * 8;
    bf16x8 qh[2], ql[2];
    qh[0] = *(const bf16x8*)(Qhi + qoff);
    qh[1] = *(const bf16x8*)(Qhi + qoff + 32);
    ql[0] = *(const bf16x8*)(Qlo + qoff);
    ql[1] = *(const bf16x8*)(Qlo + qoff + 32);

    f32x4 oacc[4];
    float m_run[4], l_run[4];
    #pragma unroll
    for (int i = 0; i < 4; ++i) {
        oacc[i] = (f32x4){0.f, 0.f, 0.f, 0.f};
        m_run[i] = -INFINITY; l_run[i] = 0.f;
    }

    const int srow = tid >> 2, sc16 = (tid & 3) * 16;
    const int swz = (srow & 7) << 4;
    const int sb0 = (srow * 128 + sc16 * 2) ^ swz;
    const int sb1 = (srow * 128 + sc16 * 2 + 16) ^ swz;

    for (int s0 = s_begin; s0 < s_end; s0 += 64) {
        __syncthreads();
        {
            const u16* gkh = Khi + hTD + (size_t)(s0 + srow) * DH + sc16;
            const u16* gkl = Klo + hTD + (size_t)(s0 + srow) * DH + sc16;
            const u16* gv  = Vt  + hTD + (size_t)srow * T + s0 + sc16;
            *(int4*)((char*)KsH + sb0) = *(const int4*)gkh;
            *(int4*)((char*)KsH + sb1) = *(const int4*)(gkh + 8);
            *(int4*)((char*)KsL + sb0) = *(const int4*)gkl;
            *(int4*)((char*)KsL + sb1) = *(const int4*)(gkl + 8);
            *(int4*)((char*)Vs  + sb0) = *(const int4*)gv;
            *(int4*)((char*)Vs  + sb1) = *(const int4*)(gv + 8);
        }
        __syncthreads();

        f32x4 acc[4];
        #pragma unroll
        for (int ct = 0; ct < 4; ++ct) acc[ct] = (f32x4){0.f, 0.f, 0.f, 0.f};
        #pragma unroll
        for (int ct = 0; ct < 4; ++ct) {
            #pragma unroll
            for (int ks = 0; ks < 2; ++ks) {
                int row = 16 * ct + b;
                int byt = (row * 128 + ks * 64 + a * 16) ^ ((row & 7) << 4);
                bf16x8 kh = *(const bf16x8*)((const char*)KsH + byt);
                bf16x8 kl = *(const bf16x8*)((const char*)KsL + byt);
                acc[ct] = MFMA16(qh[ks], kh, acc[ct]);
                acc[ct] = MFMA16(qh[ks], kl, acc[ct]);
                acc[ct] = MFMA16(ql[ks], kh, acc[ct]);
            }
        }

        #pragma unroll
        for (int r = 0; r < 4; ++r) {
            int t = t0 + 16 * w + a * 4 + r;
            const u16* aprow = AP + (size_t)t * T + s0 + b;
            #pragma unroll
            for (int ct = 0; ct < 4; ++ct)
                acc[ct][r] += b2f(aprow[16 * ct]);
        }

        #pragma unroll
        for (int r = 0; r < 4; ++r) {
            float mx = fmaxf(fmaxf(acc[0][r], acc[1][r]), fmaxf(acc[2][r], acc[3][r]));
            #pragma unroll
            for (int msk = 8; msk > 0; msk >>= 1) mx = fmaxf(mx, __shfl_xor(mx, msk));
            float mnew  = fmaxf(m_run[r], mx);
            float alpha = __expf(m_run[r] - mnew);   // first tile: 0
            float p0 = __expf(acc[0][r] - mnew);
            float p1 = __expf(acc[1][r] - mnew);
            float p2 = __expf(acc[2][r] - mnew);
            float p3 = __expf(acc[3][r] - mnew);
            float rs = p0 + p1 + p2 + p3;
            #pragma unroll
            for (int msk = 8; msk > 0; msk >>= 1) rs += __shfl_xor(rs, msk);
            l_run[r] = l_run[r] * alpha + rs;
            m_run[r] = mnew;
            oacc[0][r] *= alpha; oacc[1][r] *= alpha;
            oacc[2][r] *= alpha; oacc[3][r] *= alpha;
            int rl = a * 4 + r;
            int rbase = rl * 128, rswz = (rl & 7) << 4;
            *(u16*)((char*)Ps[w] + ((rbase + (b     ) * 2) ^ rswz)) = f2b(p0);
            *(u16*)((char*)Ps[w] + ((rbase + (b + 16) * 2) ^ rswz)) = f2b(p1);
            *(u16*)((char*)Ps[w] + ((rbase + (b + 32) * 2) ^ rswz)) = f2b(p2);
            *(u16*)((char*)Ps[w] + ((rbase + (b + 48) * 2) ^ rswz)) = f2b(p3);
        }

        bf16x8 pa[2];
        #pragma unroll
        for (int ks = 0; ks < 2; ++ks) {
            int byt = (b * 128 + ks * 64 + a * 16) ^ ((b & 7) << 4);
            pa[ks] = *(const bf16x8*)((const char*)Ps[w] + byt);
        }
        #pragma unroll
        for (int dt = 0; dt < 4; ++dt) {
            #pragma unroll
            for (int ks = 0; ks < 2; ++ks) {
                int row = 16 * dt + b;
                int byt = (row * 128 + ks * 64 + a * 16) ^ ((row & 7) << 4);
                bf16x8 vf = *(const bf16x8*)((const char*)Vs + byt);
                oacc[dt] = MFMA16(pa[ks], vf, oacc[dt]);
            }
        }
    }

    const size_t pbase = ((size_t)split * NH + h) * T;
    #pragma unroll
    for (int r = 0; r < 4; ++r) {
        int t = t0 + 16 * w + a * 4 + r;
        #pragma unroll
        for (int dt = 0; dt < 4; ++dt)
            Opart[(pbase + t) * DH + 16 * dt + b] = f2b(oacc[dt][r]);
        if (b == 0) ml[pbase + t] = make_float2(m_run[r], l_run[r]);
    }
}

// ---------------------------------------------------------------------------
// Combine split-K partials: Yc = (w0*O0 + w1*O1) / (w0*l0 + w1*l1)
// ---------------------------------------------------------------------------
__global__ __launch_bounds__(256) void flash_combine(
    const u16* __restrict__ Opart, const float2* __restrict__ ml,
    u16* __restrict__ Ycb)
{
    int idx = blockIdx.x * 256 + threadIdx.x;          // NH*T*8 total
    int h = idx >> 14;
    int rem = idx & 16383;
    int t = rem >> 3;
    int d8 = (rem & 7) * 8;

    const size_t r0 = ((size_t)0 * NH + h) * T + t;
    const size_t r1 = ((size_t)1 * NH + h) * T + t;
    float2 ml0 = ml[r0], ml1 = ml[r1];
    float m = fmaxf(ml0.x, ml1.x);
    float w0 = __expf(ml0.x - m), w1 = __expf(ml1.x - m);
    float inv = 1.f / (w0 * ml0.y + w1 * ml1.y);
    w0 *= inv; w1 *= inv;

    union { u16 u[8]; int4 v; } o0, o1, yo;
    o0.v = *(const int4*)(Opart + r0 * DH + d8);
    o1.v = *(const int4*)(Opart + r1 * DH + d8);
    #pragma unroll
    for (int j = 0; j < 8; ++j)
        yo.u[j] = f2b(b2f(o0.u[j]) * w0 + b2f(o1.u[j]) * w1);
    *(int4*)(Ycb + (size_t)t * Dm + h * DH + d8) = yo.v;
}

// ---------------------------------------------------------------------------
// Head-15 scores via MFMA (split QK) + AP -> fp32 S   (validated r9/r10)
// ---------------------------------------------------------------------------
__global__ __launch_bounds__(256) void score_mfma(
    const u16* __restrict__ Qhi, const u16* __restrict__ Qlo,
    const u16* __restrict__ Khi, const u16* __restrict__ Klo,
    const u16* __restrict__ AP, float* __restrict__ S)
{
    __shared__ u16 KsH[4096];
    __shared__ u16 KsL[4096];

    const int h = NH - 1;
    const int s0 = blockIdx.x * 64, t0 = blockIdx.y * 64;
    const int tid = threadIdx.x, w = tid >> 6, lane = tid & 63;
    const int b = lane & 15, a = lane >> 4;
    const size_t hTD = (size_t)h * T * DH;

    {
        const int srow = tid >> 2, sc16 = (tid & 3) * 16;
        const int swz = (srow & 7) << 4;
        const int sb0 = (srow * 128 + sc16 * 2) ^ swz;
        const int sb1 = (srow * 128 + sc16 * 2 + 16) ^ swz;
        const u16* gkh = Khi + hTD + (size_t)(s0 + srow) * DH + sc16;
        const u16* gkl = Klo + hTD + (size_t)(s0 + srow) * DH + sc16;
        *(int4*)((char*)KsH + sb0) = *(const int4*)gkh;
        *(int4*)((char*)KsH + sb1) = *(const int4*)(gkh + 8);
        *(int4*)((char*)KsL + sb0) = *(const int4*)gkl;
        *(int4*)((char*)KsL + sb1) = *(const int4*)(gkl + 8);
    }

    const size_t qoff = hTD + (size_t)(t0 + 16*w + b) * DH + a * 8;
    bf16x8 qh[2], ql[2];
    qh[0] = *(const bf16x8*)(Qhi + qoff);
    qh[1] = *(const bf16x8*)(Qhi + qoff + 32);
    ql[0] = *(const bf16x8*)(Qlo + qoff);
    ql[1] = *(const bf16x8*)(Qlo + qoff + 32);
    __syncthreads();

    f32x4 acc[4];
    #pragma unroll
    for (int ct = 0; ct < 4; ++ct) acc[ct] = (f32x4){0.f, 0.f, 0.f, 0.f};
    #pragma unroll
    for (int ct = 0; ct < 4; ++ct) {
        #pragma unroll
        for (int ks = 0; ks < 2; ++ks) {
            int row = 16 * ct + b;
            int byt = (row * 128 + ks * 64 + a * 16) ^ ((row & 7) << 4);
            bf16x8 kh = *(const bf16x8*)((const char*)KsH + byt);
            bf16x8 kl = *(const bf16x8*)((const char*)KsL + byt);
            acc[ct] = MFMA16(qh[ks], kh, acc[ct]);
            acc[ct] = MFMA16(qh[ks], kl, acc[ct]);
            acc[ct] = MFMA16(ql[ks], kh, acc[ct]);
        }
    }

    #pragma unroll
    for (int r = 0; r < 4; ++r) {
        int t = t0 + 16 * w + a * 4 + r;
        const u16* aprow = AP + (size_t)t * T + s0 + b;
        #pragma unroll
        for (int ct = 0; ct < 4; ++ct)
            S[(size_t)t * T + s0 + 16 * ct + b] = acc[ct][r] + b2f(aprow[16 * ct]);
    }
}

// ---------------------------------------------------------------------------
__global__ __launch_bounds__(256) void softmax_kernel(float* __restrict__ Sbase)
{
    float* S = Sbase + (long)blockIdx.x * T;
    const int tid = threadIdx.x;
    const int wid = tid >> 6, lane = tid & 63;

    float4 v0 = *(const float4*)(S + tid*8);
    float4 v1 = *(const float4*)(S + tid*8 + 4);

    float m = fmaxf(fmaxf(fmaxf(v0.x, v0.y), fmaxf(v0.z, v0.w)),
                    fmaxf(fmaxf(v1.x, v1.y), fmaxf(v1.z, v1.w)));
    #pragma unroll
    for (int o = 32; o > 0; o >>= 1) m = fmaxf(m, __shfl_xor(m, o));

    __shared__ float redm[4];
    __shared__ float reds[4];
    if (lane == 0) redm[wid] = m;
    __syncthreads();
    m = fmaxf(fmaxf(redm[0], redm[1]), fmaxf(redm[2], redm[3]));

    v0.x = expf(v0.x - m); v0.y = expf(v0.y - m); v0.z = expf(v0.z - m); v0.w = expf(v0.w - m);
    v1.x = expf(v1.x - m); v1.y = expf(v1.y - m); v1.z = expf(v1.z - m); v1.w = expf(v1.w - m);

    float s = v0.x + v0.y + v0.z + v0.w + v1.x + v1.y + v1.z + v1.w;
    #pragma unroll
    for (int o = 32; o > 0; o >>= 1) s += __shfl_xor(s, o);
    if (lane == 0) reds[wid] = s;
    __syncthreads();
    s = reds[0] + reds[1] + reds[2] + reds[3];

    float inv = 1.0f / s;
    v0.x *= inv; v0.y *= inv; v0.z *= inv; v0.w *= inv;
    v1.x *= inv; v1.y *= inv; v1.z *= inv; v1.w *= inv;
    *(float4*)(S + tid*8)     = v0;
    *(float4*)(S + tid*8 + 4) = v1;
}

// ---------------------------------------------------------------------------
// y = Ycb(bf16) @ Woutb(bf16)^T via MFMA with LDS staging (validated r10)
// ---------------------------------------------------------------------------
__global__ __launch_bounds__(256) void gemm_out_mfma(
    const u16* __restrict__ Ycb, const u16* __restrict__ Wb,
    float* __restrict__ y)
{
    __shared__ u16 As[4096];
    __shared__ u16 Bs[4096];

    const int n0 = blockIdx.x * 64, t0 = blockIdx.y * 64;
    const int tid = threadIdx.x, w = tid >> 6, lane = tid & 63;
    const int b = lane & 15, a = lane >> 4;

    const int srow = tid >> 2, sc16 = (tid & 3) * 16;
    const int swz = (srow & 7) << 4;
    const int sb0 = (srow * 128 + sc16 * 2) ^ swz;
    const int sb1 = (srow * 128 + sc16 * 2 + 16) ^ swz;

    f32x4 acc[4];
    #pragma unroll
    for (int ct = 0; ct < 4; ++ct) acc[ct] = (f32x4){0.f, 0.f, 0.f, 0.f};

    for (int kc = 0; kc < Dm; kc += 64) {
        __syncthreads();
        {
            const u16* ga = Ycb + (size_t)(t0 + srow) * Dm + kc + sc16;
            const u16* gb = Wb  + (size_t)(n0 + srow) * Dm + kc + sc16;
            *(int4*)((char*)As + sb0) = *(const int4*)ga;
            *(int4*)((char*)As + sb1) = *(const int4*)(ga + 8);
            *(int4*)((char*)Bs + sb0) = *(const int4*)gb;
            *(int4*)((char*)Bs + sb1) = *(const int4*)(gb + 8);
        }
        __syncthreads();

        bf16x8 af[2];
        #pragma unroll
        for (int ks = 0; ks < 2; ++ks) {
            int row = 16 * w + b;
            int byt = (row * 128 + ks * 64 + a * 16) ^ ((row & 7) << 4);
            af[ks] = *(const bf16x8*)((const char*)As + byt);
        }
        #pragma unroll
        for (int ct = 0; ct < 4; ++ct) {
            #pragma unroll
            for (int ks = 0; ks < 2; ++ks) {
                int row = 16 * ct + b;
                int byt = (row * 128 + ks * 64 + a * 16) ^ ((row & 7) << 4);
                bf16x8 bw = *(const bf16x8*)((const char*)Bs + byt);
                acc[ct] = MFMA16(af[ks], bw, acc[ct]);
            }
        }
    }

    #pragma unroll
    for (int r = 0; r < 4; ++r) {
        int t = t0 + 16 * w + a * 4 + r;
        #pragma unroll
        for (int ct = 0; ct < 4; ++ct)
            y[(size_t)t * Dm + n0 + 16 * ct + b] = acc[ct][r];
    }
}

// ---------------------------------------------------------------------------
extern "C" void kernel_launch(void* const* d_in, const int* in_sizes, int n_in,
                              void* d_out, int out_size, void* d_ws, size_t ws_size,
                              hipStream_t stream)
{
    const float* x    = (const float*)d_in[0];
    const float* Wq   = (const float*)d_in[1];
    const float* Wk   = (const float*)d_in[2];
    const float* Wv   = (const float*)d_in[3];
    const float* Wout = (const float*)d_in[4];

    float* out      = (float*)d_out;
    float* y_out    = out;
    float* attn_out = out + (long)T * Dm;     // 16 MB region, written LAST by
                                              // score+softmax -> free scratch
                                              // for the flash split partials.

    // ---- workspace layout (34 MB, proven) ----
    char* ws = (char*)d_ws;
    const size_t MB = 1024 * 1024;
    float* invfreq = (float*)ws;                       // 8 KB
    u16* Qhi = (u16*)(ws + 8192);                      // 4 MB each
    u16* Qlo = (u16*)(ws + 8192 + 4 * MB);
    u16* Khi = (u16*)(ws + 8192 + 8 * MB);
    u16* Klo = (u16*)(ws + 8192 + 12 * MB);
    u16* Vt  = (u16*)(ws + 8192 + 16 * MB);            // 4 MB
    char* C  = ws + 8192 + 20 * MB;                    // 14 MB union region
    u16* xhi = (u16*)(C);                              // phase 1
    u16* xlo = (u16*)(C + 4 * MB);
    u16* Wtb = (u16*)(C + 8 * MB);
    u16* APt   = (u16*)(C);                            // phase 2
    u16* Ycb   = (u16*)(C + 8 * MB);
    u16* Woutb = (u16*)(C + 12 * MB);
    // split-K partials live in d_out's attn region (overwritten later):
    u16*    Opart = (u16*)attn_out;                    // 8 MB
    float2* mlbuf = (float2*)((char*)attn_out + 8 * MB); // 512 KB
    (void)ws_size;

    invfreq_kernel<<<dim3(8), dim3(256), 0, stream>>>(invfreq);

    xsplit_kernel<<<dim3((T * Dm / 4) / 256), dim3(256), 0, stream>>>(x, xhi, xlo);
    wtrans_kernel<<<dim3(Dm / 64, NH, 3), dim3(256), 0, stream>>>(Wq, Wk, Wv, Wtb);

    proj_mfma<<<dim3(T / 64, NH), dim3(256), 0, stream>>>(
        xhi, xlo, Wtb, Qhi, Qlo, Khi, Klo, Vt);

    ap_kernel<<<dim3(T / 512, T), dim3(256), 0, stream>>>(invfreq, APt);
    wout_conv_kernel<<<dim3((Dm * Dm / 4) / 256), dim3(256), 0, stream>>>(Wout, Woutb);

    // split-K flash (partials in d_out attn region) + combine -> Ycb
    flash_mfma_split<<<dim3(T / 64, NH, 2), dim3(256), 0, stream>>>(
        Qhi, Qlo, Khi, Klo, Vt, APt, Opart, mlbuf);
    flash_combine<<<dim3(NH * T * 8 / 256), dim3(256), 0, stream>>>(
        Opart, mlbuf, Ycb);

    // head-15 attention map (overwrites the scratch region)
    score_mfma<<<dim3(T / 64, T / 64), dim3(256), 0, stream>>>(
        Qhi, Qlo, Khi, Klo, APt, attn_out);
    softmax_kernel<<<dim3(T), dim3(256), 0, stream>>>(attn_out);

    gemm_out_mfma<<<dim3(Dm / 64, T / 64), dim3(256), 0, stream>>>(Ycb, Woutb, y_out);
}

// Round 13
// 192.518 us; speedup vs baseline: 1.0648x; 1.0326x over previous
//
#include <hip/hip_runtime.h>
#include <hip/hip_bf16.h>
#include <math.h>

constexpr int T  = 2048;
constexpr int Dm = 1024;
constexpr int NH = 16;
constexpr int DH = 64;

typedef unsigned short u16;
typedef short bf16x8 __attribute__((ext_vector_type(8)));
typedef float f32x4 __attribute__((ext_vector_type(4)));

#define MFMA16(a, b, c) __builtin_amdgcn_mfma_f32_16x16x32_bf16((a), (b), (c), 0, 0, 0)

__device__ __forceinline__ float b2f(u16 h) {
    union { unsigned int u; float f; } v; v.u = ((unsigned int)h) << 16; return v.f;
}
__device__ __forceinline__ u16 f2b(float f) {   // RNE via HW cvt (was 5-op sw RNE)
    __hip_bfloat16 h = __float2bfloat16(f);
    union { __hip_bfloat16 h; u16 u; } v; v.h = h; return v.u;
}

// ---------------------------------------------------------------------------
__global__ __launch_bounds__(256) void invfreq_kernel(float* __restrict__ invfreq) {
    int c = blockIdx.x * 256 + threadIdx.x;
    if (c < T) {
        float e = (float)(c & ~1) / (float)Dm;
        invfreq[c] = powf(10000.0f, -e);
    }
}

// ---------------------------------------------------------------------------
// Transposed AP table: APT[s][t] = sin/cos(t*invfreq[s])  (parity of s picks)
// ---------------------------------------------------------------------------
__global__ __launch_bounds__(256) void ap_kernel(const float* __restrict__ invfreq,
                                                 u16* __restrict__ apt) {
    int p = blockIdx.x * 256 + threadIdx.x;   // t-pair index
    int s = blockIdx.y;
    int t = p * 2;
    float f = invfreq[s];
    float v0, v1;
    if (s & 1) { v0 = __cosf((float)t * f); v1 = __cosf((float)(t + 1) * f); }
    else       { v0 = __sinf((float)t * f); v1 = __sinf((float)(t + 1) * f); }
    unsigned int packed = (unsigned int)f2b(v0) | ((unsigned int)f2b(v1) << 16);
    *(unsigned int*)(apt + (size_t)s * T + t) = packed;
}

// ---------------------------------------------------------------------------
__global__ __launch_bounds__(256) void xsplit_kernel(const float* __restrict__ x,
                                                     u16* __restrict__ xhi,
                                                     u16* __restrict__ xlo) {
    size_t i = ((size_t)blockIdx.x * 256 + threadIdx.x) * 4;
    float4 v = *(const float4*)(x + i);
    ushort4 hv, lv;
    hv.x = f2b(v.x); hv.y = f2b(v.y); hv.z = f2b(v.z); hv.w = f2b(v.w);
    lv.x = f2b(v.x - b2f(hv.x)); lv.y = f2b(v.y - b2f(hv.y));
    lv.z = f2b(v.z - b2f(hv.z)); lv.w = f2b(v.w - b2f(hv.w));
    *(ushort4*)(xhi + i) = hv;
    *(ushort4*)(xlo + i) = lv;
}

// ---------------------------------------------------------------------------
__global__ __launch_bounds__(256) void wtrans_kernel(
    const float* __restrict__ Wq, const float* __restrict__ Wk,
    const float* __restrict__ Wv, u16* __restrict__ Wt)
{
    const int z = blockIdx.z;
    const float* W = (z == 0) ? Wq : (z == 1) ? Wk : Wv;
    const int h = blockIdx.y, kc = blockIdx.x * 64;
    const int tid = threadIdx.x;

    __shared__ float Ls[64][65];
    #pragma unroll
    for (int it = 0; it < 4; ++it) {
        int idx = it * 256 + tid;
        int kl = idx >> 4, n4 = (idx & 15) * 4;
        float4 v = *(const float4*)(W + ((size_t)h * Dm + kc + kl) * DH + n4);
        Ls[n4+0][kl] = v.x; Ls[n4+1][kl] = v.y; Ls[n4+2][kl] = v.z; Ls[n4+3][kl] = v.w;
    }
    __syncthreads();

    const int n = tid >> 2, k16 = (tid & 3) * 16;
    union { u16 u[16]; int4 v[2]; } tmp;
    #pragma unroll
    for (int j = 0; j < 16; ++j) tmp.u[j] = f2b(Ls[n][k16 + j]);
    u16* dst = Wt + (((size_t)z * NH + h) * DH + n) * Dm + kc + k16;
    *(int4*)(dst)     = tmp.v[0];
    *(int4*)(dst + 8) = tmp.v[1];
}

// ---------------------------------------------------------------------------
__global__ __launch_bounds__(256) void wout_conv_kernel(const float* __restrict__ W,
                                                        u16* __restrict__ Wb) {
    size_t i = ((size_t)blockIdx.x * 256 + threadIdx.x) * 4;
    float4 v = *(const float4*)(W + i);
    ushort4 hv;
    hv.x = f2b(v.x); hv.y = f2b(v.y); hv.z = f2b(v.z); hv.w = f2b(v.w);
    *(ushort4*)(Wb + i) = hv;
}

// ---------------------------------------------------------------------------
// Fused QKV projection via MFMA + swizzled LDS staging (validated r10).
// ---------------------------------------------------------------------------
__global__ __launch_bounds__(256) void proj_mfma(
    const u16* __restrict__ xhi, const u16* __restrict__ xlo,
    const u16* __restrict__ Wt,
    u16* __restrict__ Qhi, u16* __restrict__ Qlo,
    u16* __restrict__ Khi, u16* __restrict__ Klo,
    u16* __restrict__ Vt)
{
    __shared__ u16 XsH[4096];
    __shared__ u16 XsL[4096];
    __shared__ u16 WsQ[4096];
    __shared__ u16 WsK[4096];
    __shared__ u16 WsV[4096];

    const int t0 = blockIdx.x * 64, h = blockIdx.y;
    const int tid = threadIdx.x, w = tid >> 6, lane = tid & 63;
    const int b = lane & 15, a = lane >> 4;

    const int srow = tid >> 2, sc16 = (tid & 3) * 16;
    const int swz = (srow & 7) << 4;
    const int sb0 = (srow * 128 + sc16 * 2) ^ swz;
    const int sb1 = (srow * 128 + sc16 * 2 + 16) ^ swz;

    const u16* WQb = Wt + ((size_t)0 * NH + h) * DH * Dm;
    const u16* WKb = Wt + ((size_t)1 * NH + h) * DH * Dm;
    const u16* WVb = Wt + ((size_t)2 * NH + h) * DH * Dm;

    f32x4 aq[4], ak[4], av[4];
    #pragma unroll
    for (int ct = 0; ct < 4; ++ct) {
        aq[ct] = (f32x4){0.f, 0.f, 0.f, 0.f};
        ak[ct] = (f32x4){0.f, 0.f, 0.f, 0.f};
        av[ct] = (f32x4){0.f, 0.f, 0.f, 0.f};
    }

    for (int kc = 0; kc < Dm; kc += 64) {
        __syncthreads();
        {
            const u16* gxh = xhi + (size_t)(t0 + srow) * Dm + kc + sc16;
            const u16* gxl = xlo + (size_t)(t0 + srow) * Dm + kc + sc16;
            const u16* gwq = WQb + (size_t)srow * Dm + kc + sc16;
            const u16* gwk = WKb + (size_t)srow * Dm + kc + sc16;
            const u16* gwv = WVb + (size_t)srow * Dm + kc + sc16;
            *(int4*)((char*)XsH + sb0) = *(const int4*)gxh;
            *(int4*)((char*)XsH + sb1) = *(const int4*)(gxh + 8);
            *(int4*)((char*)XsL + sb0) = *(const int4*)gxl;
            *(int4*)((char*)XsL + sb1) = *(const int4*)(gxl + 8);
            *(int4*)((char*)WsQ + sb0) = *(const int4*)gwq;
            *(int4*)((char*)WsQ + sb1) = *(const int4*)(gwq + 8);
            *(int4*)((char*)WsK + sb0) = *(const int4*)gwk;
            *(int4*)((char*)WsK + sb1) = *(const int4*)(gwk + 8);
            *(int4*)((char*)WsV + sb0) = *(const int4*)gwv;
            *(int4*)((char*)WsV + sb1) = *(const int4*)(gwv + 8);
        }
        __syncthreads();

        bf16x8 ah[2], al[2];
        #pragma unroll
        for (int ks = 0; ks < 2; ++ks) {
            int row = 16 * w + b;
            int byt = (row * 128 + ks * 64 + a * 16) ^ ((row & 7) << 4);
            ah[ks] = *(const bf16x8*)((const char*)XsH + byt);
            al[ks] = *(const bf16x8*)((const char*)XsL + byt);
        }
        #pragma unroll
        for (int ct = 0; ct < 4; ++ct) {
            #pragma unroll
            for (int ks = 0; ks < 2; ++ks) {
                int row = 16 * ct + b;
                int byt = (row * 128 + ks * 64 + a * 16) ^ ((row & 7) << 4);
                bf16x8 bq = *(const bf16x8*)((const char*)WsQ + byt);
                bf16x8 bk = *(const bf16x8*)((const char*)WsK + byt);
                bf16x8 bv = *(const bf16x8*)((const char*)WsV + byt);
                aq[ct] = MFMA16(ah[ks], bq, aq[ct]);
                aq[ct] = MFMA16(al[ks], bq, aq[ct]);
                ak[ct] = MFMA16(ah[ks], bk, ak[ct]);
                ak[ct] = MFMA16(al[ks], bk, ak[ct]);
                av[ct] = MFMA16(ah[ks], bv, av[ct]);
            }
        }
    }

    const size_t base = (size_t)h * T * DH;
    #pragma unroll
    for (int ct = 0; ct < 4; ++ct) {
        #pragma unroll
        for (int r = 0; r < 4; ++r) {
            int t = t0 + 16 * w + a * 4 + r;
            size_t off = base + (size_t)t * DH + 16 * ct + b;
            float fq = aq[ct][r];
            u16 qv = f2b(fq);
            Qhi[off] = qv; Qlo[off] = f2b(fq - b2f(qv));
            float fk = ak[ct][r];
            u16 kv = f2b(fk);
            Khi[off] = kv; Klo[off] = f2b(fk - b2f(kv));
            Vt[((size_t)h * DH + 16 * ct + b) * T + t] = f2b(av[ct][r]);
        }
    }
}

// ---------------------------------------------------------------------------
// MFMA flash attention, split-K (2 splits). Unnormalized bf16 partial O +
// (m,l) per row. AP read from transposed table as 8B loads, issued early.
// ---------------------------------------------------------------------------
__global__ __launch_bounds__(256) void flash_mfma_split(
    const u16* __restrict__ Qhi, const u16* __restrict__ Qlo,
    const u16* __restrict__ Khi, const u16* __restrict__ Klo,
    const u16* __restrict__ Vt,  const u16* __restrict__ APT,
    u16* __restrict__ Opart, float2* __restrict__ ml)
{
    __shared__ u16 KsH[4096];
    __shared__ u16 KsL[4096];
    __shared__ u16 Vs[4096];
    __shared__ u16 Ps[4][1024];

    const int h = blockIdx.y, t0 = blockIdx.x * 64;
    const int split = blockIdx.z;
    const int s_begin = split * (T / 2), s_end = s_begin + T / 2;
    const int tid = threadIdx.x, w = tid >> 6, lane = tid & 63;
    const int b = lane & 15, a = lane >> 4;

    const size_t hTD = (size_t)h * T * DH;
    const int trow4 = t0 + 16 * w + a * 4;    // first of this lane's 4 t-rows

    const size_t qoff = hTD + (size_t)(t0 + 16*w + b) * DH + a * 8;
    bf16x8 qh[2], ql[2];
    qh[0] = *(const bf16x8*)(Qhi + qoff);
    qh[1] = *(const bf16x8*)(Qhi + qoff + 32);
    ql[0] = *(const bf16x8*)(Qlo + qoff);
    ql[1] = *(const bf16x8*)(Qlo + qoff + 32);

    f32x4 oacc[4];
    float m_run[4], l_run[4];
    #pragma unroll
    for (int i = 0; i < 4; ++i) {
        oacc[i] = (f32x4){0.f, 0.f, 0.f, 0.f};
        m_run[i] = -INFINITY; l_run[i] = 0.f;
    }

    const int srow = tid >> 2, sc16 = (tid & 3) * 16;
    const int swz = (srow & 7) << 4;
    const int sb0 = (srow * 128 + sc16 * 2) ^ swz;
    const int sb1 = (srow * 128 + sc16 * 2 + 16) ^ swz;

    for (int s0 = s_begin; s0 < s_end; s0 += 64) {
        __syncthreads();
        {
            const u16* gkh = Khi + hTD + (size_t)(s0 + srow) * DH + sc16;
            const u16* gkl = Klo + hTD + (size_t)(s0 + srow) * DH + sc16;
            const u16* gv  = Vt  + hTD + (size_t)srow * T + s0 + sc16;
            *(int4*)((char*)KsH + sb0) = *(const int4*)gkh;
            *(int4*)((char*)KsH + sb1) = *(const int4*)(gkh + 8);
            *(int4*)((char*)KsL + sb0) = *(const int4*)gkl;
            *(int4*)((char*)KsL + sb1) = *(const int4*)(gkl + 8);
            *(int4*)((char*)Vs  + sb0) = *(const int4*)gv;
            *(int4*)((char*)Vs  + sb1) = *(const int4*)(gv + 8);
        }
        __syncthreads();

        // AP bias loads issued first: latency hides under the QK^T MFMAs
        ushort4 ap4[4];
        #pragma unroll
        for (int ct = 0; ct < 4; ++ct)
            ap4[ct] = *(const ushort4*)(APT + (size_t)(s0 + b + 16 * ct) * T + trow4);

        f32x4 acc[4];
        #pragma unroll
        for (int ct = 0; ct < 4; ++ct) acc[ct] = (f32x4){0.f, 0.f, 0.f, 0.f};
        #pragma unroll
        for (int ct = 0; ct < 4; ++ct) {
            #pragma unroll
            for (int ks = 0; ks < 2; ++ks) {
                int row = 16 * ct + b;
                int byt = (row * 128 + ks * 64 + a * 16) ^ ((row & 7) << 4);
                bf16x8 kh = *(const bf16x8*)((const char*)KsH + byt);
                bf16x8 kl = *(const bf16x8*)((const char*)KsL + byt);
                acc[ct] = MFMA16(qh[ks], kh, acc[ct]);
                acc[ct] = MFMA16(qh[ks], kl, acc[ct]);
                acc[ct] = MFMA16(ql[ks], kh, acc[ct]);
            }
        }

        #pragma unroll
        for (int ct = 0; ct < 4; ++ct) {
            const u16* apu = (const u16*)&ap4[ct];
            #pragma unroll
            for (int r = 0; r < 4; ++r)
                acc[ct][r] += b2f(apu[r]);
        }

        #pragma unroll
        for (int r = 0; r < 4; ++r) {
            float mx = fmaxf(fmaxf(acc[0][r], acc[1][r]), fmaxf(acc[2][r], acc[3][r]));
            #pragma unroll
            for (int msk = 8; msk > 0; msk >>= 1) mx = fmaxf(mx, __shfl_xor(mx, msk));
            float mnew  = fmaxf(m_run[r], mx);
            float alpha = __expf(m_run[r] - mnew);   // first tile: 0
            float p0 = __expf(acc[0][r] - mnew);
            float p1 = __expf(acc[1][r] - mnew);
            float p2 = __expf(acc[2][r] - mnew);
            float p3 = __expf(acc[3][r] - mnew);
            float rs = p0 + p1 + p2 + p3;
            #pragma unroll
            for (int msk = 8; msk > 0; msk >>= 1) rs += __shfl_xor(rs, msk);
            l_run[r] = l_run[r] * alpha + rs;
            m_run[r] = mnew;
            oacc[0][r] *= alpha; oacc[1][r] *= alpha;
            oacc[2][r] *= alpha; oacc[3][r] *= alpha;
            int rl = a * 4 + r;
            int rbase = rl * 128, rswz = (rl & 7) << 4;
            *(u16*)((char*)Ps[w] + ((rbase + (b     ) * 2) ^ rswz)) = f2b(p0);
            *(u16*)((char*)Ps[w] + ((rbase + (b + 16) * 2) ^ rswz)) = f2b(p1);
            *(u16*)((char*)Ps[w] + ((rbase + (b + 32) * 2) ^ rswz)) = f2b(p2);
            *(u16*)((char*)Ps[w] + ((rbase + (b + 48) * 2) ^ rswz)) = f2b(p3);
        }

        bf16x8 pa[2];
        #pragma unroll
        for (int ks = 0; ks < 2; ++ks) {
            int byt = (b * 128 + ks * 64 + a * 16) ^ ((b & 7) << 4);
            pa[ks] = *(const bf16x8*)((const char*)Ps[w] + byt);
        }
        #pragma unroll
        for (int dt = 0; dt < 4; ++dt) {
            #pragma unroll
            for (int ks = 0; ks < 2; ++ks) {
                int row = 16 * dt + b;
                int byt = (row * 128 + ks * 64 + a * 16) ^ ((row & 7) << 4);
                bf16x8 vf = *(const bf16x8*)((const char*)Vs + byt);
                oacc[dt] = MFMA16(pa[ks], vf, oacc[dt]);
            }
        }
    }

    const size_t pbase = ((size_t)split * NH + h) * T;
    #pragma unroll
    for (int r = 0; r < 4; ++r) {
        int t = trow4 + r;
        #pragma unroll
        for (int dt = 0; dt < 4; ++dt)
            Opart[(pbase + t) * DH + 16 * dt + b] = f2b(oacc[dt][r]);
        if (b == 0) ml[pbase + t] = make_float2(m_run[r], l_run[r]);
    }
}

// ---------------------------------------------------------------------------
// Combine split-K partials; also store (m*, 1/L) for head 15 (softmax fusion)
// ---------------------------------------------------------------------------
__global__ __launch_bounds__(256) void flash_combine(
    const u16* __restrict__ Opart, const float2* __restrict__ ml,
    u16* __restrict__ Ycb, float2* __restrict__ mlfinal)
{
    int idx = blockIdx.x * 256 + threadIdx.x;          // NH*T*8 total
    int h = idx >> 14;
    int rem = idx & 16383;
    int t = rem >> 3;
    int d8 = (rem & 7) * 8;

    const size_t r0 = ((size_t)0 * NH + h) * T + t;
    const size_t r1 = ((size_t)1 * NH + h) * T + t;
    float2 ml0 = ml[r0], ml1 = ml[r1];
    float m = fmaxf(ml0.x, ml1.x);
    float w0 = __expf(ml0.x - m), w1 = __expf(ml1.x - m);
    float inv = 1.f / (w0 * ml0.y + w1 * ml1.y);
    if (h == NH - 1 && d8 == 0) mlfinal[t] = make_float2(m, inv);
    w0 *= inv; w1 *= inv;

    union { u16 u[8]; int4 v; } o0, o1, yo;
    o0.v = *(const int4*)(Opart + r0 * DH + d8);
    o1.v = *(const int4*)(Opart + r1 * DH + d8);
    #pragma unroll
    for (int j = 0; j < 8; ++j)
        yo.u[j] = f2b(b2f(o0.u[j]) * w0 + b2f(o1.u[j]) * w1);
    *(int4*)(Ycb + (size_t)t * Dm + h * DH + d8) = yo.v;
}

// ---------------------------------------------------------------------------
// Head-15 attention map, softmax fused: P = exp(S - m*) * (1/L) from combine.
// ---------------------------------------------------------------------------
__global__ __launch_bounds__(256) void score_mfma(
    const u16* __restrict__ Qhi, const u16* __restrict__ Qlo,
    const u16* __restrict__ Khi, const u16* __restrict__ Klo,
    const u16* __restrict__ APT, const float2* __restrict__ mlf,
    float* __restrict__ S)
{
    __shared__ u16 KsH[4096];
    __shared__ u16 KsL[4096];

    const int h = NH - 1;
    const int s0 = blockIdx.x * 64, t0 = blockIdx.y * 64;
    const int tid = threadIdx.x, w = tid >> 6, lane = tid & 63;
    const int b = lane & 15, a = lane >> 4;
    const size_t hTD = (size_t)h * T * DH;
    const int trow4 = t0 + 16 * w + a * 4;

    {
        const int srow = tid >> 2, sc16 = (tid & 3) * 16;
        const int swz = (srow & 7) << 4;
        const int sb0 = (srow * 128 + sc16 * 2) ^ swz;
        const int sb1 = (srow * 128 + sc16 * 2 + 16) ^ swz;
        const u16* gkh = Khi + hTD + (size_t)(s0 + srow) * DH + sc16;
        const u16* gkl = Klo + hTD + (size_t)(s0 + srow) * DH + sc16;
        *(int4*)((char*)KsH + sb0) = *(const int4*)gkh;
        *(int4*)((char*)KsH + sb1) = *(const int4*)(gkh + 8);
        *(int4*)((char*)KsL + sb0) = *(const int4*)gkl;
        *(int4*)((char*)KsL + sb1) = *(const int4*)(gkl + 8);
    }

    const size_t qoff = hTD + (size_t)(t0 + 16*w + b) * DH + a * 8;
    bf16x8 qh[2], ql[2];
    qh[0] = *(const bf16x8*)(Qhi + qoff);
    qh[1] = *(const bf16x8*)(Qhi + qoff + 32);
    ql[0] = *(const bf16x8*)(Qlo + qoff);
    ql[1] = *(const bf16x8*)(Qlo + qoff + 32);
    __syncthreads();

    // AP + (m*, 1/L) loads issued early
    ushort4 ap4[4];
    #pragma unroll
    for (int ct = 0; ct < 4; ++ct)
        ap4[ct] = *(const ushort4*)(APT + (size_t)(s0 + b + 16 * ct) * T + trow4);
    float2 f[4];
    #pragma unroll
    for (int r = 0; r < 4; ++r) f[r] = mlf[trow4 + r];

    f32x4 acc[4];
    #pragma unroll
    for (int ct = 0; ct < 4; ++ct) acc[ct] = (f32x4){0.f, 0.f, 0.f, 0.f};
    #pragma unroll
    for (int ct = 0; ct < 4; ++ct) {
        #pragma unroll
        for (int ks = 0; ks < 2; ++ks) {
            int row = 16 * ct + b;
            int byt = (row * 128 + ks * 64 + a * 16) ^ ((row & 7) << 4);
            bf16x8 kh = *(const bf16x8*)((const char*)KsH + byt);
            bf16x8 kl = *(const bf16x8*)((const char*)KsL + byt);
            acc[ct] = MFMA16(qh[ks], kh, acc[ct]);
            acc[ct] = MFMA16(qh[ks], kl, acc[ct]);
            acc[ct] = MFMA16(ql[ks], kh, acc[ct]);
        }
    }

    #pragma unroll
    for (int ct = 0; ct < 4; ++ct) {
        const u16* apu = (const u16*)&ap4[ct];
        #pragma unroll
        for (int r = 0; r < 4; ++r) {
            float sval = acc[ct][r] + b2f(apu[r]);
            S[(size_t)(trow4 + r) * T + s0 + 16 * ct + b] =
                __expf(sval - f[r].x) * f[r].y;
        }
    }
}

// ---------------------------------------------------------------------------
// y = Ycb(bf16) @ Woutb(bf16)^T via MFMA with LDS staging (validated r10)
// ---------------------------------------------------------------------------
__global__ __launch_bounds__(256) void gemm_out_mfma(
    const u16* __restrict__ Ycb, const u16* __restrict__ Wb,
    float* __restrict__ y)
{
    __shared__ u16 As[4096];
    __shared__ u16 Bs[4096];

    const int n0 = blockIdx.x * 64, t0 = blockIdx.y * 64;
    const int tid = threadIdx.x, w = tid >> 6, lane = tid & 63;
    const int b = lane & 15, a = lane >> 4;

    const int srow = tid >> 2, sc16 = (tid & 3) * 16;
    const int swz = (srow & 7) << 4;
    const int sb0 = (srow * 128 + sc16 * 2) ^ swz;
    const int sb1 = (srow * 128 + sc16 * 2 + 16) ^ swz;

    f32x4 acc[4];
    #pragma unroll
    for (int ct = 0; ct < 4; ++ct) acc[ct] = (f32x4){0.f, 0.f, 0.f, 0.f};

    for (int kc = 0; kc < Dm; kc += 64) {
        __syncthreads();
        {
            const u16* ga = Ycb + (size_t)(t0 + srow) * Dm + kc + sc16;
            const u16* gb = Wb  + (size_t)(n0 + srow) * Dm + kc + sc16;
            *(int4*)((char*)As + sb0) = *(const int4*)ga;
            *(int4*)((char*)As + sb1) = *(const int4*)(ga + 8);
            *(int4*)((char*)Bs + sb0) = *(const int4*)gb;
            *(int4*)((char*)Bs + sb1) = *(const int4*)(gb + 8);
        }
        __syncthreads();

        bf16x8 af[2];
        #pragma unroll
        for (int ks = 0; ks < 2; ++ks) {
            int row = 16 * w + b;
            int byt = (row * 128 + ks * 64 + a * 16) ^ ((row & 7) << 4);
            af[ks] = *(const bf16x8*)((const char*)As + byt);
        }
        #pragma unroll
        for (int ct = 0; ct < 4; ++ct) {
            #pragma unroll
            for (int ks = 0; ks < 2; ++ks) {
                int row = 16 * ct + b;
                int byt = (row * 128 + ks * 64 + a * 16) ^ ((row & 7) << 4);
                bf16x8 bw = *(const bf16x8*)((const char*)Bs + byt);
                acc[ct] = MFMA16(af[ks], bw, acc[ct]);
            }
        }
    }

    #pragma unroll
    for (int r = 0; r < 4; ++r) {
        int t = t0 + 16 * w + a * 4 + r;
        #pragma unroll
        for (int ct = 0; ct < 4; ++ct)
            y[(size_t)t * Dm + n0 + 16 * ct + b] = acc[ct][r];
    }
}

// ---------------------------------------------------------------------------
extern "C" void kernel_launch(void* const* d_in, const int* in_sizes, int n_in,
                              void* d_out, int out_size, void* d_ws, size_t ws_size,
                              hipStream_t stream)
{
    const float* x    = (const float*)d_in[0];
    const float* Wq   = (const float*)d_in[1];
    const float* Wk   = (const float*)d_in[2];
    const float* Wv   = (const float*)d_in[3];
    const float* Wout = (const float*)d_in[4];

    float* out      = (float*)d_out;
    float* y_out    = out;
    float* attn_out = out + (long)T * Dm;     // written LAST -> usable scratch

    // ---- workspace layout (34.3 MB; 34.5 MB proven) ----
    char* ws = (char*)d_ws;
    const size_t MB = 1024 * 1024;
    float* invfreq = (float*)ws;                       // 8 KB
    u16* Qhi = (u16*)(ws + 8192);                      // 4 MB each
    u16* Qlo = (u16*)(ws + 8192 + 4 * MB);
    u16* Khi = (u16*)(ws + 8192 + 8 * MB);
    u16* Klo = (u16*)(ws + 8192 + 12 * MB);
    u16* Vt  = (u16*)(ws + 8192 + 16 * MB);            // 4 MB
    char* C  = ws + 8192 + 20 * MB;
    u16* xhi = (u16*)(C);                              // phase 1
    u16* xlo = (u16*)(C + 4 * MB);
    u16* Wtb = (u16*)(C + 8 * MB);
    u16* APt   = (u16*)(C);                            // phase 2 (transposed)
    u16* Ycb   = (u16*)(C + 8 * MB);
    u16* Woutb = (u16*)(C + 12 * MB);
    float2* mlfinal = (float2*)(C + 14 * MB);          // 16 KB (head-15 m*,1/L)
    // split-K partials in d_out attn region (overwritten later by score):
    u16*    Opart = (u16*)attn_out;                    // 8 MB
    float2* mlbuf = (float2*)((char*)attn_out + 8 * MB); // 512 KB
    (void)ws_size;

    invfreq_kernel<<<dim3(8), dim3(256), 0, stream>>>(invfreq);

    xsplit_kernel<<<dim3((T * Dm / 4) / 256), dim3(256), 0, stream>>>(x, xhi, xlo);
    wtrans_kernel<<<dim3(Dm / 64, NH, 3), dim3(256), 0, stream>>>(Wq, Wk, Wv, Wtb);

    proj_mfma<<<dim3(T / 64, NH), dim3(256), 0, stream>>>(
        xhi, xlo, Wtb, Qhi, Qlo, Khi, Klo, Vt);

    ap_kernel<<<dim3(T / 512, T), dim3(256), 0, stream>>>(invfreq, APt);
    wout_conv_kernel<<<dim3((Dm * Dm / 4) / 256), dim3(256), 0, stream>>>(Wout, Woutb);

    flash_mfma_split<<<dim3(T / 64, NH, 2), dim3(256), 0, stream>>>(
        Qhi, Qlo, Khi, Klo, Vt, APt, Opart, mlbuf);
    flash_combine<<<dim3(NH * T * 8 / 256), dim3(256), 0, stream>>>(
        Opart, mlbuf, Ycb, mlfinal);

    // head-15 attention map with fused softmax (overwrites scratch region)
    score_mfma<<<dim3(T / 64, T / 64), dim3(256), 0, stream>>>(
        Qhi, Qlo, Khi, Klo, APt, mlfinal, attn_out);

    gemm_out_mfma<<<dim3(Dm / 64, T / 64), dim3(256), 0, stream>>>(Ycb, Woutb, y_out);
}

// Round 14
// 149.696 us; speedup vs baseline: 1.3694x; 1.2861x over previous
//
#include <hip/hip_runtime.h>
#include <math.h>

constexpr int T  = 2048;
constexpr int Dm = 1024;
constexpr int NH = 16;
constexpr int DH = 64;

typedef unsigned short u16;
typedef _Float16 f16;
typedef f16 f16x8 __attribute__((ext_vector_type(8)));
typedef float f32x4 __attribute__((ext_vector_type(4)));

#define MFMAH(a, b, c) __builtin_amdgcn_mfma_f32_16x16x32_f16((a), (b), (c), 0, 0, 0)

__device__ __forceinline__ float h2f(u16 h) {
    union { u16 u; f16 h; } v; v.u = h; return (float)v.h;
}
__device__ __forceinline__ u16 f2h(float f) {   // RNE via v_cvt_f16_f32
    union { u16 u; f16 h; } v; v.h = (f16)f; return v.u;
}

// ---------------------------------------------------------------------------
__global__ __launch_bounds__(256) void invfreq_kernel(float* __restrict__ invfreq) {
    int c = blockIdx.x * 256 + threadIdx.x;
    if (c < T) {
        float e = (float)(c & ~1) / (float)Dm;
        invfreq[c] = powf(10000.0f, -e);
    }
}

// ---------------------------------------------------------------------------
// Transposed AP table (fp16): APT[s][t] = sin/cos(t*invfreq[s])
// ---------------------------------------------------------------------------
__global__ __launch_bounds__(256) void ap_kernel(const float* __restrict__ invfreq,
                                                 u16* __restrict__ apt) {
    int p = blockIdx.x * 256 + threadIdx.x;   // t-pair index
    int s = blockIdx.y;
    int t = p * 2;
    float f = invfreq[s];
    float v0, v1;
    if (s & 1) { v0 = __cosf((float)t * f); v1 = __cosf((float)(t + 1) * f); }
    else       { v0 = __sinf((float)t * f); v1 = __sinf((float)(t + 1) * f); }
    unsigned int packed = (unsigned int)f2h(v0) | ((unsigned int)f2h(v1) << 16);
    *(unsigned int*)(apt + (size_t)s * T + t) = packed;
}

// ---------------------------------------------------------------------------
// x fp32 -> fp16
// ---------------------------------------------------------------------------
__global__ __launch_bounds__(256) void xconv_kernel(const float* __restrict__ x,
                                                    u16* __restrict__ xh) {
    size_t i = ((size_t)blockIdx.x * 256 + threadIdx.x) * 4;
    float4 v = *(const float4*)(x + i);
    ushort4 hv;
    hv.x = f2h(v.x); hv.y = f2h(v.y); hv.z = f2h(v.z); hv.w = f2h(v.w);
    *(ushort4*)(xh + i) = hv;
}

// ---------------------------------------------------------------------------
// W[h][k][n] fp32 -> Wt[(z,h)][n][k] fp16  (transpose + convert)
// ---------------------------------------------------------------------------
__global__ __launch_bounds__(256) void wtrans_kernel(
    const float* __restrict__ Wq, const float* __restrict__ Wk,
    const float* __restrict__ Wv, u16* __restrict__ Wt)
{
    const int z = blockIdx.z;
    const float* W = (z == 0) ? Wq : (z == 1) ? Wk : Wv;
    const int h = blockIdx.y, kc = blockIdx.x * 64;
    const int tid = threadIdx.x;

    __shared__ float Ls[64][65];
    #pragma unroll
    for (int it = 0; it < 4; ++it) {
        int idx = it * 256 + tid;
        int kl = idx >> 4, n4 = (idx & 15) * 4;
        float4 v = *(const float4*)(W + ((size_t)h * Dm + kc + kl) * DH + n4);
        Ls[n4+0][kl] = v.x; Ls[n4+1][kl] = v.y; Ls[n4+2][kl] = v.z; Ls[n4+3][kl] = v.w;
    }
    __syncthreads();

    const int n = tid >> 2, k16 = (tid & 3) * 16;
    union { u16 u[16]; int4 v[2]; } tmp;
    #pragma unroll
    for (int j = 0; j < 16; ++j) tmp.u[j] = f2h(Ls[n][k16 + j]);
    u16* dst = Wt + (((size_t)z * NH + h) * DH + n) * Dm + kc + k16;
    *(int4*)(dst)     = tmp.v[0];
    *(int4*)(dst + 8) = tmp.v[1];
}

// ---------------------------------------------------------------------------
// Wout fp32 -> fp16
// ---------------------------------------------------------------------------
__global__ __launch_bounds__(256) void wout_conv_kernel(const float* __restrict__ W,
                                                        u16* __restrict__ Wb) {
    size_t i = ((size_t)blockIdx.x * 256 + threadIdx.x) * 4;
    float4 v = *(const float4*)(W + i);
    ushort4 hv;
    hv.x = f2h(v.x); hv.y = f2h(v.y); hv.z = f2h(v.z); hv.w = f2h(v.w);
    *(ushort4*)(Wb + i) = hv;
}

// ---------------------------------------------------------------------------
// Fused QKV projection, fp16 MFMA + swizzled LDS staging. Q,K fp16 out;
// V fp16 transposed out. (r10-validated structure, dtype-swapped.)
// ---------------------------------------------------------------------------
__global__ __launch_bounds__(256) void proj_mfma(
    const u16* __restrict__ xh, const u16* __restrict__ Wt,
    u16* __restrict__ Qh, u16* __restrict__ Kh, u16* __restrict__ Vt)
{
    __shared__ u16 Xs[4096];
    __shared__ u16 WsQ[4096];
    __shared__ u16 WsK[4096];
    __shared__ u16 WsV[4096];

    const int t0 = blockIdx.x * 64, h = blockIdx.y;
    const int tid = threadIdx.x, w = tid >> 6, lane = tid & 63;
    const int b = lane & 15, a = lane >> 4;

    const int srow = tid >> 2, sc16 = (tid & 3) * 16;
    const int swz = (srow & 7) << 4;
    const int sb0 = (srow * 128 + sc16 * 2) ^ swz;
    const int sb1 = (srow * 128 + sc16 * 2 + 16) ^ swz;

    const u16* WQb = Wt + ((size_t)0 * NH + h) * DH * Dm;
    const u16* WKb = Wt + ((size_t)1 * NH + h) * DH * Dm;
    const u16* WVb = Wt + ((size_t)2 * NH + h) * DH * Dm;

    f32x4 aq[4], ak[4], av[4];
    #pragma unroll
    for (int ct = 0; ct < 4; ++ct) {
        aq[ct] = (f32x4){0.f, 0.f, 0.f, 0.f};
        ak[ct] = (f32x4){0.f, 0.f, 0.f, 0.f};
        av[ct] = (f32x4){0.f, 0.f, 0.f, 0.f};
    }

    for (int kc = 0; kc < Dm; kc += 64) {
        __syncthreads();
        {
            const u16* gx  = xh  + (size_t)(t0 + srow) * Dm + kc + sc16;
            const u16* gwq = WQb + (size_t)srow * Dm + kc + sc16;
            const u16* gwk = WKb + (size_t)srow * Dm + kc + sc16;
            const u16* gwv = WVb + (size_t)srow * Dm + kc + sc16;
            *(int4*)((char*)Xs  + sb0) = *(const int4*)gx;
            *(int4*)((char*)Xs  + sb1) = *(const int4*)(gx + 8);
            *(int4*)((char*)WsQ + sb0) = *(const int4*)gwq;
            *(int4*)((char*)WsQ + sb1) = *(const int4*)(gwq + 8);
            *(int4*)((char*)WsK + sb0) = *(const int4*)gwk;
            *(int4*)((char*)WsK + sb1) = *(const int4*)(gwk + 8);
            *(int4*)((char*)WsV + sb0) = *(const int4*)gwv;
            *(int4*)((char*)WsV + sb1) = *(const int4*)(gwv + 8);
        }
        __syncthreads();

        f16x8 ax[2];
        #pragma unroll
        for (int ks = 0; ks < 2; ++ks) {
            int row = 16 * w + b;
            int byt = (row * 128 + ks * 64 + a * 16) ^ ((row & 7) << 4);
            ax[ks] = *(const f16x8*)((const char*)Xs + byt);
        }
        #pragma unroll
        for (int ct = 0; ct < 4; ++ct) {
            #pragma unroll
            for (int ks = 0; ks < 2; ++ks) {
                int row = 16 * ct + b;
                int byt = (row * 128 + ks * 64 + a * 16) ^ ((row & 7) << 4);
                f16x8 bq = *(const f16x8*)((const char*)WsQ + byt);
                f16x8 bk = *(const f16x8*)((const char*)WsK + byt);
                f16x8 bv = *(const f16x8*)((const char*)WsV + byt);
                aq[ct] = MFMAH(ax[ks], bq, aq[ct]);
                ak[ct] = MFMAH(ax[ks], bk, ak[ct]);
                av[ct] = MFMAH(ax[ks], bv, av[ct]);
            }
        }
    }

    const size_t base = (size_t)h * T * DH;
    #pragma unroll
    for (int ct = 0; ct < 4; ++ct) {
        #pragma unroll
        for (int r = 0; r < 4; ++r) {
            int t = t0 + 16 * w + a * 4 + r;
            size_t off = base + (size_t)t * DH + 16 * ct + b;
            Qh[off] = f2h(aq[ct][r]);
            Kh[off] = f2h(ak[ct][r]);
            Vt[((size_t)h * DH + 16 * ct + b) * T + t] = f2h(av[ct][r]);
        }
    }
}

// ---------------------------------------------------------------------------
// fp16 MFMA flash attention, split-K (2 splits). Unnormalized fp16 partial O
// + (m,l) per row. 8 QK^T + 8 PV MFMAs per tile (was 24+8 with split-bf16).
// ---------------------------------------------------------------------------
__global__ __launch_bounds__(256) void flash_mfma_split(
    const u16* __restrict__ Qh, const u16* __restrict__ Kh,
    const u16* __restrict__ Vt, const u16* __restrict__ APT,
    u16* __restrict__ Opart, float2* __restrict__ ml)
{
    __shared__ u16 Ks[4096];
    __shared__ u16 Vs[4096];
    __shared__ u16 Ps[4][1024];

    const int h = blockIdx.y, t0 = blockIdx.x * 64;
    const int split = blockIdx.z;
    const int s_begin = split * (T / 2), s_end = s_begin + T / 2;
    const int tid = threadIdx.x, w = tid >> 6, lane = tid & 63;
    const int b = lane & 15, a = lane >> 4;

    const size_t hTD = (size_t)h * T * DH;
    const int trow4 = t0 + 16 * w + a * 4;

    const size_t qoff = hTD + (size_t)(t0 + 16*w + b) * DH + a * 8;
    f16x8 qf[2];
    qf[0] = *(const f16x8*)(Qh + qoff);
    qf[1] = *(const f16x8*)(Qh + qoff + 32);

    f32x4 oacc[4];
    float m_run[4], l_run[4];
    #pragma unroll
    for (int i = 0; i < 4; ++i) {
        oacc[i] = (f32x4){0.f, 0.f, 0.f, 0.f};
        m_run[i] = -INFINITY; l_run[i] = 0.f;
    }

    const int srow = tid >> 2, sc16 = (tid & 3) * 16;
    const int swz = (srow & 7) << 4;
    const int sb0 = (srow * 128 + sc16 * 2) ^ swz;
    const int sb1 = (srow * 128 + sc16 * 2 + 16) ^ swz;

    for (int s0 = s_begin; s0 < s_end; s0 += 64) {
        __syncthreads();
        {
            const u16* gk = Kh + hTD + (size_t)(s0 + srow) * DH + sc16;
            const u16* gv = Vt + hTD + (size_t)srow * T + s0 + sc16;
            *(int4*)((char*)Ks + sb0) = *(const int4*)gk;
            *(int4*)((char*)Ks + sb1) = *(const int4*)(gk + 8);
            *(int4*)((char*)Vs + sb0) = *(const int4*)gv;
            *(int4*)((char*)Vs + sb1) = *(const int4*)(gv + 8);
        }
        __syncthreads();

        // AP bias loads issued first: latency hides under the QK^T MFMAs
        ushort4 ap4[4];
        #pragma unroll
        for (int ct = 0; ct < 4; ++ct)
            ap4[ct] = *(const ushort4*)(APT + (size_t)(s0 + b + 16 * ct) * T + trow4);

        f32x4 acc[4];
        #pragma unroll
        for (int ct = 0; ct < 4; ++ct) acc[ct] = (f32x4){0.f, 0.f, 0.f, 0.f};
        #pragma unroll
        for (int ct = 0; ct < 4; ++ct) {
            #pragma unroll
            for (int ks = 0; ks < 2; ++ks) {
                int row = 16 * ct + b;
                int byt = (row * 128 + ks * 64 + a * 16) ^ ((row & 7) << 4);
                f16x8 kf = *(const f16x8*)((const char*)Ks + byt);
                acc[ct] = MFMAH(qf[ks], kf, acc[ct]);
            }
        }

        #pragma unroll
        for (int ct = 0; ct < 4; ++ct) {
            const u16* apu = (const u16*)&ap4[ct];
            #pragma unroll
            for (int r = 0; r < 4; ++r)
                acc[ct][r] += h2f(apu[r]);
        }

        #pragma unroll
        for (int r = 0; r < 4; ++r) {
            float mx = fmaxf(fmaxf(acc[0][r], acc[1][r]), fmaxf(acc[2][r], acc[3][r]));
            #pragma unroll
            for (int msk = 8; msk > 0; msk >>= 1) mx = fmaxf(mx, __shfl_xor(mx, msk));
            float mnew  = fmaxf(m_run[r], mx);
            float alpha = __expf(m_run[r] - mnew);   // first tile: 0
            float p0 = __expf(acc[0][r] - mnew);
            float p1 = __expf(acc[1][r] - mnew);
            float p2 = __expf(acc[2][r] - mnew);
            float p3 = __expf(acc[3][r] - mnew);
            float rs = p0 + p1 + p2 + p3;
            #pragma unroll
            for (int msk = 8; msk > 0; msk >>= 1) rs += __shfl_xor(rs, msk);
            l_run[r] = l_run[r] * alpha + rs;
            m_run[r] = mnew;
            oacc[0][r] *= alpha; oacc[1][r] *= alpha;
            oacc[2][r] *= alpha; oacc[3][r] *= alpha;
            int rl = a * 4 + r;
            int rbase = rl * 128, rswz = (rl & 7) << 4;
            *(u16*)((char*)Ps[w] + ((rbase + (b     ) * 2) ^ rswz)) = f2h(p0);
            *(u16*)((char*)Ps[w] + ((rbase + (b + 16) * 2) ^ rswz)) = f2h(p1);
            *(u16*)((char*)Ps[w] + ((rbase + (b + 32) * 2) ^ rswz)) = f2h(p2);
            *(u16*)((char*)Ps[w] + ((rbase + (b + 48) * 2) ^ rswz)) = f2h(p3);
        }

        f16x8 pa[2];
        #pragma unroll
        for (int ks = 0; ks < 2; ++ks) {
            int byt = (b * 128 + ks * 64 + a * 16) ^ ((b & 7) << 4);
            pa[ks] = *(const f16x8*)((const char*)Ps[w] + byt);
        }
        #pragma unroll
        for (int dt = 0; dt < 4; ++dt) {
            #pragma unroll
            for (int ks = 0; ks < 2; ++ks) {
                int row = 16 * dt + b;
                int byt = (row * 128 + ks * 64 + a * 16) ^ ((row & 7) << 4);
                f16x8 vf = *(const f16x8*)((const char*)Vs + byt);
                oacc[dt] = MFMAH(pa[ks], vf, oacc[dt]);
            }
        }
    }

    const size_t pbase = ((size_t)split * NH + h) * T;
    #pragma unroll
    for (int r = 0; r < 4; ++r) {
        int t = trow4 + r;
        #pragma unroll
        for (int dt = 0; dt < 4; ++dt)
            Opart[(pbase + t) * DH + 16 * dt + b] = f2h(oacc[dt][r]);
        if (b == 0) ml[pbase + t] = make_float2(m_run[r], l_run[r]);
    }
}

// ---------------------------------------------------------------------------
// Combine split-K partials; stores (m*, 1/L) for head 15 softmax fusion.
// ---------------------------------------------------------------------------
__global__ __launch_bounds__(256) void flash_combine(
    const u16* __restrict__ Opart, const float2* __restrict__ ml,
    u16* __restrict__ Ych, float2* __restrict__ mlfinal)
{
    int idx = blockIdx.x * 256 + threadIdx.x;          // NH*T*8 total
    int h = idx >> 14;
    int rem = idx & 16383;
    int t = rem >> 3;
    int d8 = (rem & 7) * 8;

    const size_t r0 = ((size_t)0 * NH + h) * T + t;
    const size_t r1 = ((size_t)1 * NH + h) * T + t;
    float2 ml0 = ml[r0], ml1 = ml[r1];
    float m = fmaxf(ml0.x, ml1.x);
    float w0 = __expf(ml0.x - m), w1 = __expf(ml1.x - m);
    float inv = 1.f / (w0 * ml0.y + w1 * ml1.y);
    if (h == NH - 1 && d8 == 0) mlfinal[t] = make_float2(m, inv);
    w0 *= inv; w1 *= inv;

    union { u16 u[8]; int4 v; } o0, o1, yo;
    o0.v = *(const int4*)(Opart + r0 * DH + d8);
    o1.v = *(const int4*)(Opart + r1 * DH + d8);
    #pragma unroll
    for (int j = 0; j < 8; ++j)
        yo.u[j] = f2h(h2f(o0.u[j]) * w0 + h2f(o1.u[j]) * w1);
    *(int4*)(Ych + (size_t)t * Dm + h * DH + d8) = yo.v;
}

// ---------------------------------------------------------------------------
// Head-15 attention map, softmax fused: P = exp(S - m*) * (1/L).
// S bitwise-identical to flash's (same fp16 MFMA on same fragments).
// ---------------------------------------------------------------------------
__global__ __launch_bounds__(256) void score_mfma(
    const u16* __restrict__ Qh, const u16* __restrict__ Kh,
    const u16* __restrict__ APT, const float2* __restrict__ mlf,
    float* __restrict__ S)
{
    __shared__ u16 Ks[4096];

    const int h = NH - 1;
    const int s0 = blockIdx.x * 64, t0 = blockIdx.y * 64;
    const int tid = threadIdx.x, w = tid >> 6, lane = tid & 63;
    const int b = lane & 15, a = lane >> 4;
    const size_t hTD = (size_t)h * T * DH;
    const int trow4 = t0 + 16 * w + a * 4;

    {
        const int srow = tid >> 2, sc16 = (tid & 3) * 16;
        const int swz = (srow & 7) << 4;
        const int sb0 = (srow * 128 + sc16 * 2) ^ swz;
        const int sb1 = (srow * 128 + sc16 * 2 + 16) ^ swz;
        const u16* gk = Kh + hTD + (size_t)(s0 + srow) * DH + sc16;
        *(int4*)((char*)Ks + sb0) = *(const int4*)gk;
        *(int4*)((char*)Ks + sb1) = *(const int4*)(gk + 8);
    }

    const size_t qoff = hTD + (size_t)(t0 + 16*w + b) * DH + a * 8;
    f16x8 qf[2];
    qf[0] = *(const f16x8*)(Qh + qoff);
    qf[1] = *(const f16x8*)(Qh + qoff + 32);
    __syncthreads();

    ushort4 ap4[4];
    #pragma unroll
    for (int ct = 0; ct < 4; ++ct)
        ap4[ct] = *(const ushort4*)(APT + (size_t)(s0 + b + 16 * ct) * T + trow4);
    float2 f[4];
    #pragma unroll
    for (int r = 0; r < 4; ++r) f[r] = mlf[trow4 + r];

    f32x4 acc[4];
    #pragma unroll
    for (int ct = 0; ct < 4; ++ct) acc[ct] = (f32x4){0.f, 0.f, 0.f, 0.f};
    #pragma unroll
    for (int ct = 0; ct < 4; ++ct) {
        #pragma unroll
        for (int ks = 0; ks < 2; ++ks) {
            int row = 16 * ct + b;
            int byt = (row * 128 + ks * 64 + a * 16) ^ ((row & 7) << 4);
            f16x8 kf = *(const f16x8*)((const char*)Ks + byt);
            acc[ct] = MFMAH(qf[ks], kf, acc[ct]);
        }
    }

    #pragma unroll
    for (int ct = 0; ct < 4; ++ct) {
        const u16* apu = (const u16*)&ap4[ct];
        #pragma unroll
        for (int r = 0; r < 4; ++r) {
            float sval = acc[ct][r] + h2f(apu[r]);
            S[(size_t)(trow4 + r) * T + s0 + 16 * ct + b] =
                __expf(sval - f[r].x) * f[r].y;
        }
    }
}

// ---------------------------------------------------------------------------
// y = Ych(fp16) @ Woutb(fp16)^T via MFMA with LDS staging
// ---------------------------------------------------------------------------
__global__ __launch_bounds__(256) void gemm_out_mfma(
    const u16* __restrict__ Ych, const u16* __restrict__ Wb,
    float* __restrict__ y)
{
    __shared__ u16 As[4096];
    __shared__ u16 Bs[4096];

    const int n0 = blockIdx.x * 64, t0 = blockIdx.y * 64;
    const int tid = threadIdx.x, w = tid >> 6, lane = tid & 63;
    const int b = lane & 15, a = lane >> 4;

    const int srow = tid >> 2, sc16 = (tid & 3) * 16;
    const int swz = (srow & 7) << 4;
    const int sb0 = (srow * 128 + sc16 * 2) ^ swz;
    const int sb1 = (srow * 128 + sc16 * 2 + 16) ^ swz;

    f32x4 acc[4];
    #pragma unroll
    for (int ct = 0; ct < 4; ++ct) acc[ct] = (f32x4){0.f, 0.f, 0.f, 0.f};

    for (int kc = 0; kc < Dm; kc += 64) {
        __syncthreads();
        {
            const u16* ga = Ych + (size_t)(t0 + srow) * Dm + kc + sc16;
            const u16* gb = Wb  + (size_t)(n0 + srow) * Dm + kc + sc16;
            *(int4*)((char*)As + sb0) = *(const int4*)ga;
            *(int4*)((char*)As + sb1) = *(const int4*)(ga + 8);
            *(int4*)((char*)Bs + sb0) = *(const int4*)gb;
            *(int4*)((char*)Bs + sb1) = *(const int4*)(gb + 8);
        }
        __syncthreads();

        f16x8 af[2];
        #pragma unroll
        for (int ks = 0; ks < 2; ++ks) {
            int row = 16 * w + b;
            int byt = (row * 128 + ks * 64 + a * 16) ^ ((row & 7) << 4);
            af[ks] = *(const f16x8*)((const char*)As + byt);
        }
        #pragma unroll
        for (int ct = 0; ct < 4; ++ct) {
            #pragma unroll
            for (int ks = 0; ks < 2; ++ks) {
                int row = 16 * ct + b;
                int byt = (row * 128 + ks * 64 + a * 16) ^ ((row & 7) << 4);
                f16x8 bw = *(const f16x8*)((const char*)Bs + byt);
                acc[ct] = MFMAH(af[ks], bw, acc[ct]);
            }
        }
    }

    #pragma unroll
    for (int r = 0; r < 4; ++r) {
        int t = t0 + 16 * w + a * 4 + r;
        #pragma unroll
        for (int ct = 0; ct < 4; ++ct)
            y[(size_t)t * Dm + n0 + 16 * ct + b] = acc[ct][r];
    }
}

// ---------------------------------------------------------------------------
extern "C" void kernel_launch(void* const* d_in, const int* in_sizes, int n_in,
                              void* d_out, int out_size, void* d_ws, size_t ws_size,
                              hipStream_t stream)
{
    const float* x    = (const float*)d_in[0];
    const float* Wq   = (const float*)d_in[1];
    const float* Wk   = (const float*)d_in[2];
    const float* Wv   = (const float*)d_in[3];
    const float* Wout = (const float*)d_in[4];

    float* out      = (float*)d_out;
    float* y_out    = out;
    float* attn_out = out + (long)T * Dm;     // written LAST -> usable scratch

    // ---- workspace layout (~26 MB; 34.3 MB proven) ----
    char* ws = (char*)d_ws;
    const size_t MB = 1024 * 1024;
    float* invfreq = (float*)ws;                       // 8 KB
    u16* Qh = (u16*)(ws + 8192);                       // 4 MB
    u16* Kh = (u16*)(ws + 8192 + 4 * MB);              // 4 MB
    u16* Vt = (u16*)(ws + 8192 + 8 * MB);              // 4 MB
    char* C = ws + 8192 + 12 * MB;
    u16* xh  = (u16*)(C);                              // phase 1: 4 MB
    u16* Wtb = (u16*)(C + 4 * MB);                     //          6 MB
    u16* APt   = (u16*)(C);                            // phase 2: 8 MB
    u16* Ych   = (u16*)(C + 8 * MB);                   //          4 MB
    u16* Woutb = (u16*)(C + 12 * MB);                  //          2 MB
    float2* mlfinal = (float2*)(C + 14 * MB);          //          16 KB
    // split-K partials in d_out attn region (overwritten later by score):
    u16*    Opart = (u16*)attn_out;                    // 8 MB
    float2* mlbuf = (float2*)((char*)attn_out + 8 * MB); // 512 KB
    (void)ws_size;

    invfreq_kernel<<<dim3(8), dim3(256), 0, stream>>>(invfreq);

    xconv_kernel<<<dim3((T * Dm / 4) / 256), dim3(256), 0, stream>>>(x, xh);
    wtrans_kernel<<<dim3(Dm / 64, NH, 3), dim3(256), 0, stream>>>(Wq, Wk, Wv, Wtb);

    proj_mfma<<<dim3(T / 64, NH), dim3(256), 0, stream>>>(xh, Wtb, Qh, Kh, Vt);

    ap_kernel<<<dim3(T / 512, T), dim3(256), 0, stream>>>(invfreq, APt);
    wout_conv_kernel<<<dim3((Dm * Dm / 4) / 256), dim3(256), 0, stream>>>(Wout, Woutb);

    flash_mfma_split<<<dim3(T / 64, NH, 2), dim3(256), 0, stream>>>(
        Qh, Kh, Vt, APt, Opart, mlbuf);
    flash_combine<<<dim3(NH * T * 8 / 256), dim3(256), 0, stream>>>(
        Opart, mlbuf, Ych, mlfinal);

    // head-15 attention map with fused softmax (overwrites scratch region)
    score_mfma<<<dim3(T / 64, T / 64), dim3(256), 0, stream>>>(
        Qh, Kh, APt, mlfinal, attn_out);

    gemm_out_mfma<<<dim3(Dm / 64, T / 64), dim3(256), 0, stream>>>(Ych, Woutb, y_out);
}